// Round 17
// baseline (251.804 us; speedup 1.0000x reference)
//
#include <hip/hip_runtime.h>

// ---------------------------------------------------------------------------
// CustomCrossAttentionMinimal on MI355X (gfx950)
// b=16, i=4096, j=77, qd=320, cd=768, H=8, DH=40, inner=320
// Layouts: qhm/hohm are head-major fp16 [b][h][4096][40]
// ---------------------------------------------------------------------------

typedef _Float16 vh8 __attribute__((ext_vector_type(8)));
typedef _Float16 vh4 __attribute__((ext_vector_type(4)));
typedef float    vf4 __attribute__((ext_vector_type(4)));

#define NEGBIG  (-3.4028235e38f)
#define SCALE_F 0.15811388300841897f     // 40^-0.5
#define INFF    (__builtin_inff())

#define WAITCNT9() do { asm volatile("s_waitcnt vmcnt(9)" ::: "memory"); __builtin_amdgcn_sched_barrier(0); } while (0)
#define WAITCNT0() do { asm volatile("s_waitcnt vmcnt(0)" ::: "memory"); __builtin_amdgcn_sched_barrier(0); } while (0)
#define SBAR()     __builtin_amdgcn_s_barrier()

__device__ __forceinline__ vh8 h8zero() {
  vh8 v;
#pragma unroll
  for (int i = 0; i < 8; ++i) v[i] = (_Float16)0.f;
  return v;
}
__device__ __forceinline__ vf4 f4zero() {
  vf4 v;
#pragma unroll
  for (int i = 0; i < 4; ++i) v[i] = 0.f;
  return v;
}
__device__ __forceinline__ float gelu_exact(float x) {
  return 0.5f * x * (1.0f + erff(x * 0.70710678118654752f));
}
__device__ __forceinline__ unsigned swzA(int row) {
  return (unsigned)(((row & 7) << 4) ^ (((row >> 3) & 1) << 5));
}
__device__ __forceinline__ unsigned swzB(int row) {
  return (unsigned)((row & 7) << 4);
}
__device__ __forceinline__ void glds16(const void* g, void* l) {
  __builtin_amdgcn_global_load_lds((const __attribute__((address_space(1))) unsigned*)g,
                                   (__attribute__((address_space(3))) unsigned*)l, 16, 0, 0);
}

// ---------------------------------------------------------------------------
// Tiled weight transpose (32x32 tiles through LDS), fp32 -> fp16 [N][K]
// ---------------------------------------------------------------------------
__global__ __launch_bounds__(256) void transpose_kernel(
    const float* __restrict__ Wq, const float* __restrict__ Wk,
    const float* __restrict__ Wv, const float* __restrict__ Wo,
    _Float16* __restrict__ WqT, _Float16* __restrict__ WkvT, _Float16* __restrict__ WoT)
{
  __shared__ float ts[32][33];
  int tile = blockIdx.x;
  const float* src; _Float16* dst; int dstK, rowOff;
  if (tile < 100)      { src = Wq; dst = WqT;  dstK = 320; rowOff = 0; }
  else if (tile < 340) { src = Wk; dst = WkvT; dstK = 768; rowOff = 0;   tile -= 100; }
  else if (tile < 580) { src = Wv; dst = WkvT; dstK = 768; rowOff = 320; tile -= 340; }
  else                 { src = Wo; dst = WoT;  dstK = 320; rowOff = 0;   tile -= 580; }
  int kb = tile / 10, nb = tile - kb * 10;
  int k0 = kb * 32, n0 = nb * 32;
  int r = threadIdx.x >> 5, c = threadIdx.x & 31;
#pragma unroll
  for (int p = 0; p < 4; ++p)
    ts[r + p * 8][c] = src[(size_t)(k0 + r + p * 8) * 320 + n0 + c];
  __syncthreads();
#pragma unroll
  for (int p = 0; p < 4; ++p)
    dst[(size_t)(rowOff + n0 + r + p * 8) * dstK + k0 + c] = (_Float16)ts[c][r + p * 8];
}

// ---------------------------------------------------------------------------
// V^T pre-swizzled global: vTg[b][h][d(48)][chunk c(16)][e(8)] fp16
// ---------------------------------------------------------------------------
__global__ __launch_bounds__(256) void vtrans_kernel(
    const _Float16* __restrict__ vf, unsigned* __restrict__ vTg32)
{
  const int b = blockIdx.x, h = blockIdx.y, t = threadIdx.x;
  unsigned* out = vTg32 + (size_t)(b * 8 + h) * 3072;
#pragma unroll
  for (int p = 0; p < 12; ++p) {
    int idx = t + p * 256;
    int d = idx >> 6;
    int u = idx & 63;
    int c = u >> 2, pr = u & 3;
    int sd = (int)(swzA(d) >> 4);
    int j0 = ((c ^ sd) << 3) + pr * 2;
    unsigned lo = 0, hi = 0;
    if (d < 40) {
      if (j0 < 77)     lo = *(const unsigned short*)(vf + (size_t)(b * 77 + j0) * 640 + h * 40 + d);
      if (j0 + 1 < 77) hi = *(const unsigned short*)(vf + (size_t)(b * 77 + j0 + 1) * 640 + h * 40 + d);
    }
    out[idx] = lo | (hi << 16);
  }
}

// ---------------------------------------------------------------------------
// KV GEMM (barrier-free): C[1232,640] = embs[1232,768] @ WkvT[640,768]^T
// ---------------------------------------------------------------------------
__global__ __launch_bounds__(256) void kv_gemm_kernel(
    const float* __restrict__ Ap, const _Float16* __restrict__ Bt,
    _Float16* __restrict__ Cp)
{
  const int t = threadIdx.x, lane = t & 63, wave = t >> 6;
  const int m0 = blockIdx.x * 64;
  const int n0 = blockIdx.y * 160;
  const int l15 = lane & 15, l4 = lane >> 4;
  const int rg = wave >> 1, cg = wave & 1;

  vf4 acc[2][5];
#pragma unroll
  for (int a = 0; a < 2; ++a)
#pragma unroll
    for (int bq = 0; bq < 5; ++bq) acc[a][bq] = f4zero();

#pragma unroll 2
  for (int kk = 0; kk < 24; ++kk) {
    int k = kk * 32 + l4 * 8;
    vh8 av[2];
#pragma unroll
    for (int mt = 0; mt < 2; ++mt) {
      int row = m0 + rg * 32 + mt * 16 + l15;
      av[mt] = h8zero();
      if (row < 1232) {
        const float* ap = Ap + (size_t)row * 768 + k;
        float4 f0 = *(const float4*)ap;
        float4 f1 = *(const float4*)(ap + 4);
        vh8 hv;
        hv[0] = (_Float16)f0.x; hv[1] = (_Float16)f0.y; hv[2] = (_Float16)f0.z; hv[3] = (_Float16)f0.w;
        hv[4] = (_Float16)f1.x; hv[5] = (_Float16)f1.y; hv[6] = (_Float16)f1.z; hv[7] = (_Float16)f1.w;
        av[mt] = hv;
      }
    }
#pragma unroll
    for (int nt = 0; nt < 5; ++nt) {
      int n = n0 + cg * 80 + nt * 16 + l15;
      vh8 bv = *(const vh8*)(Bt + (size_t)n * 768 + k);
      acc[0][nt] = __builtin_amdgcn_mfma_f32_16x16x32_f16(av[0], bv, acc[0][nt], 0, 0, 0);
      acc[1][nt] = __builtin_amdgcn_mfma_f32_16x16x32_f16(av[1], bv, acc[1][nt], 0, 0, 0);
    }
  }
#pragma unroll
  for (int mt = 0; mt < 2; ++mt)
#pragma unroll
    for (int nt = 0; nt < 5; ++nt) {
      int n = n0 + cg * 80 + nt * 16 + l15;
#pragma unroll
      for (int r = 0; r < 4; ++r) {
        int m = m0 + rg * 32 + mt * 16 + l4 * 4 + r;
        if (m < 1232) Cp[(size_t)m * 640 + n] = (_Float16)acc[mt][nt][r];
      }
    }
}

// ---------------------------------------------------------------------------
// Q projection + fused std. 512 thr, 8 waves, BM=128 (2 subtiles of 64 rows).
// Counted-vmcnt 2-deep pipeline: per kc a thread issues exactly 9 VMEM ops
// (5 glds16 B + 4 float4 A); vmcnt(9) means "previous group complete".
// ---------------------------------------------------------------------------
__global__ __launch_bounds__(512) void qproj_kernel(
    const float* __restrict__ x, const _Float16* __restrict__ Bt,
    const _Float16* __restrict__ kf, const int* __restrict__ ctypes,
    _Float16* __restrict__ qhm, double* __restrict__ partials)
{
  __shared__ __align__(16) char smem[81920];   // buf0 @0, buf1 @40960; buf0 reused for re-tile
  const int t = threadIdx.x, lane = t & 63, wave = t >> 6;
  const int m0 = blockIdx.x * 128;
  const int l15 = lane & 15, l4 = lane >> 4;
  const int wbase = t & ~63;
  const int rg = wave >> 1, cg = wave & 1;          // rg 0..3, cg 0..1
  const float* arow0 = x + (size_t)(m0 + rg * 16 + l15) * 320 + l4 * 8;        // subtile 0
  const float* arow1 = x + (size_t)(m0 + 64 + rg * 16 + l15) * 320 + l4 * 8;   // subtile 1

  vf4 acc[2][10];
#pragma unroll
  for (int s = 0; s < 2; ++s)
#pragma unroll
    for (int bq = 0; bq < 10; ++bq) acc[s][bq] = f4zero();

  float4 fA[8], fB[8];   // [s*4 + ks*2 + half]

  // ---- prologue: group(0) = B(0)+A(0); group(1) = B(1)+A(1) ----
#pragma unroll
  for (int p = 0; p < 5; ++p) {
    int idx = t + p * 512;
    int n = idx >> 3, c8 = idx & 7;
    glds16(Bt + (size_t)n * 320 + 0 + ((c8 ^ (n & 7)) << 3),
           smem + (size_t)(p * 512 + wbase) * 16);
  }
#pragma unroll
  for (int ks = 0; ks < 2; ++ks) {
    fA[0 + ks * 2 + 0] = *(const float4*)(arow0 + ks * 32);
    fA[0 + ks * 2 + 1] = *(const float4*)(arow0 + ks * 32 + 4);
    fA[4 + ks * 2 + 0] = *(const float4*)(arow1 + ks * 32);
    fA[4 + ks * 2 + 1] = *(const float4*)(arow1 + ks * 32 + 4);
  }
  __builtin_amdgcn_sched_barrier(0);   // group(0) fully issued before group(1)
#pragma unroll
  for (int p = 0; p < 5; ++p) {
    int idx = t + p * 512;
    int n = idx >> 3, c8 = idx & 7;
    glds16(Bt + (size_t)n * 320 + 64 + ((c8 ^ (n & 7)) << 3),
           smem + 40960 + (size_t)(p * 512 + wbase) * 16);
  }
#pragma unroll
  for (int ks = 0; ks < 2; ++ks) {
    fB[0 + ks * 2 + 0] = *(const float4*)(arow0 + 64 + ks * 32);
    fB[0 + ks * 2 + 1] = *(const float4*)(arow0 + 64 + ks * 32 + 4);
    fB[4 + ks * 2 + 0] = *(const float4*)(arow1 + 64 + ks * 32);
    fB[4 + ks * 2 + 1] = *(const float4*)(arow1 + 64 + ks * 32 + 4);
  }
  WAITCNT9();        // group(0) complete; group(1) may remain in flight
  SBAR();

#pragma unroll
  for (int kc = 0; kc < 5; ++kc) {
    char* BsCur = smem + (size_t)(kc & 1) * 40960;
    float4* cur = (kc & 1) ? fB : fA;
    // compute tile kc
#pragma unroll
    for (int s = 0; s < 2; ++s) {
#pragma unroll
      for (int ks = 0; ks < 2; ++ks) {
        float4 f0 = cur[s * 4 + ks * 2 + 0];
        float4 f1 = cur[s * 4 + ks * 2 + 1];
        vh8 av;
        av[0] = (_Float16)f0.x; av[1] = (_Float16)f0.y; av[2] = (_Float16)f0.z; av[3] = (_Float16)f0.w;
        av[4] = (_Float16)f1.x; av[5] = (_Float16)f1.y; av[6] = (_Float16)f1.z; av[7] = (_Float16)f1.w;
#pragma unroll
        for (int nt = 0; nt < 10; ++nt) {
          int n = cg * 160 + nt * 16 + l15;
          unsigned byte = (unsigned)(n * 128 + (ks * 32 + l4 * 8) * 2) ^ swzB(n);
          vh8 bv = *(const vh8*)(BsCur + byte);
          acc[s][nt] = __builtin_amdgcn_mfma_f32_16x16x32_f16(av, bv, acc[s][nt], 0, 0, 0);
        }
      }
    }
    if (kc < 4) {
      SBAR();                      // all waves done reading buf[kc&1]
      if (kc < 3) {
        int k0n = (kc + 2) * 64;   // stage group(kc+2) into buf[kc&1]
#pragma unroll
        for (int p = 0; p < 5; ++p) {
          int idx = t + p * 512;
          int n = idx >> 3, c8 = idx & 7;
          glds16(Bt + (size_t)n * 320 + k0n + ((c8 ^ (n & 7)) << 3),
                 BsCur + (size_t)(p * 512 + wbase) * 16);
        }
#pragma unroll
        for (int ks = 0; ks < 2; ++ks) {
          cur[0 + ks * 2 + 0] = *(const float4*)(arow0 + k0n + ks * 32);
          cur[0 + ks * 2 + 1] = *(const float4*)(arow0 + k0n + ks * 32 + 4);
          cur[4 + ks * 2 + 0] = *(const float4*)(arow1 + k0n + ks * 32);
          cur[4 + ks * 2 + 1] = *(const float4*)(arow1 + k0n + ks * 32 + 4);
        }
        WAITCNT9();                // group(kc+1) complete
      } else {
        WAITCNT0();                // kc==3: group(4) complete
      }
      SBAR();                      // buf[(kc+1)&1] visible to all waves
    }
  }
  __syncthreads();                 // protect buf0 before epilogue reuse

  // per-subtile epilogue: re-tile -> scatter -> fused std
  double S = 0.0, S2 = 0.0;
  const int b = m0 >> 12;
  const int h = wave;
#pragma unroll
  for (int s = 0; s < 2; ++s) {
#pragma unroll
    for (int nt = 0; nt < 10; ++nt) {
      int col = cg * 160 + nt * 16 + l15;
#pragma unroll
      for (int r = 0; r < 4; ++r) {
        int lr = rg * 16 + l4 * 4 + r;
        unsigned byte = (unsigned)(lr * 640 + col * 2) ^ swzB(lr);
        *(_Float16*)(smem + byte) = (_Float16)acc[s][nt][r];
      }
    }
    __syncthreads();
#pragma unroll
    for (int p = 0; p < 5; ++p) {
      int idx = t + p * 512;               // 0..2559 = 64 rows x 8 heads x 5 chunks
      int hh = idx / 320;
      int rem = idx - hh * 320;
      int lrow = rem / 5;
      int c = rem - lrow * 5;
      unsigned sb = (unsigned)(lrow * 640 + hh * 80 + c * 16) ^ swzB(lrow);
      vh8 v = *(const vh8*)(smem + sb);
      int gi = m0 + s * 64 + lrow;
      int bb = gi >> 12, ii = gi & 4095;
      *(vh8*)(qhm + ((size_t)(bb * 8 + hh) * 4096 + ii) * 40 + c * 8) = v;
    }
    {
      vh8 a0v[4], a1v[4];
#pragma unroll
      for (int mt = 0; mt < 4; ++mt) {
        int qrow = mt * 16 + l15;
        unsigned b0 = (unsigned)(qrow * 640 + (h * 40 + l4 * 8) * 2) ^ swzB(qrow);
        a0v[mt] = *(const vh8*)(smem + b0);
        a1v[mt] = h8zero();
        if (l4 == 0) {
          unsigned b1 = (unsigned)(qrow * 640 + (h * 40 + 32) * 2) ^ swzB(qrow);
          a1v[mt] = *(const vh8*)(smem + b1);
        }
      }
#pragma unroll
      for (int jt = 0; jt < 5; ++jt) {
        int j = jt * 16 + l15;
        bool valid = (j < 77);
        vh8 b0 = h8zero(), b1 = h8zero();
        int ctj = -1;
        if (valid) {
          const _Float16* kp = kf + (size_t)(b * 77 + j) * 640 + h * 40;
          b0 = *(const vh8*)(kp + l4 * 8);
          if (l4 == 0) b1 = *(const vh8*)(kp + 32);
          ctj = ctypes[b * 77 + j];
        }
#pragma unroll
        for (int mt = 0; mt < 4; ++mt) {
          vf4 sv4 = f4zero();
          sv4 = __builtin_amdgcn_mfma_f32_16x16x32_f16(a0v[mt], b0, sv4, 0, 0, 0);
          sv4 = __builtin_amdgcn_mfma_f32_16x16x32_f16(a1v[mt], b1, sv4, 0, 0, 0);
          if (ctj >= 2) {
#pragma unroll
            for (int r = 0; r < 4; ++r) {
              double sv = (double)sv4[r];
              S += sv; S2 += sv * sv;
            }
          }
        }
      }
    }
    __syncthreads();
  }
#pragma unroll
  for (int off = 32; off > 0; off >>= 1) {
    S += __shfl_xor(S, off);
    S2 += __shfl_xor(S2, off);
  }
  if (lane == 0) {
    int idx = blockIdx.x * 8 + wave;
    partials[2 * idx + 0] = S;
    partials[2 * idx + 1] = S2;
  }
}

// ---------------------------------------------------------------------------
// O projection: 512 thr, 8 waves, BM=128 (2 subtiles). Counted-vmcnt 2-deep.
// Per group: 5 glds16 + 4 vh8 A-loads = 9 VMEM ops per thread.
// ---------------------------------------------------------------------------
__global__ __launch_bounds__(512) void oproj_kernel(
    const _Float16* __restrict__ hohm, const _Float16* __restrict__ Bt,
    const float* __restrict__ bias, float* __restrict__ out)
{
  __shared__ __align__(16) _Float16 Bs[2][320 * 64];   // 80 KB
  const int t = threadIdx.x, lane = t & 63, wave = t >> 6;
  const int m0 = blockIdx.x * 128;
  const int l15 = lane & 15, l4 = lane >> 4;
  const int wbase = t & ~63;
  const int rg = wave >> 1, cg = wave & 1;

  const int gi0 = m0 + rg * 16 + l15;          // subtile 0
  const int gi1 = gi0 + 64;                    // subtile 1
  const int bb0 = gi0 >> 12, ii0 = gi0 & 4095;
  const int bb1 = gi1 >> 12, ii1 = gi1 & 4095;

  vf4 acc[2][10];
#pragma unroll
  for (int s = 0; s < 2; ++s)
#pragma unroll
    for (int bq = 0; bq < 10; ++bq) acc[s][bq] = f4zero();

  vh8 hA[4], hB[4];   // [s*2 + ks]

  // ---- prologue: group(0), group(1) ----
#pragma unroll
  for (int p = 0; p < 5; ++p) {
    int idx = t + p * 512;
    int n = idx >> 3, c8 = idx & 7;
    glds16(Bt + (size_t)n * 320 + 0 + ((c8 ^ (n & 7)) << 3),
           (char*)Bs[0] + (size_t)(p * 512 + wbase) * 16);
  }
#pragma unroll
  for (int ks = 0; ks < 2; ++ks) {
    int k = ks * 32 + l4 * 8;
    int hh = k / 40, d = k - hh * 40;
    hA[0 + ks] = *(const vh8*)(hohm + ((size_t)(bb0 * 8 + hh) * 4096 + ii0) * 40 + d);
    hA[2 + ks] = *(const vh8*)(hohm + ((size_t)(bb1 * 8 + hh) * 4096 + ii1) * 40 + d);
  }
  __builtin_amdgcn_sched_barrier(0);
#pragma unroll
  for (int p = 0; p < 5; ++p) {
    int idx = t + p * 512;
    int n = idx >> 3, c8 = idx & 7;
    glds16(Bt + (size_t)n * 320 + 64 + ((c8 ^ (n & 7)) << 3),
           (char*)Bs[1] + (size_t)(p * 512 + wbase) * 16);
  }
#pragma unroll
  for (int ks = 0; ks < 2; ++ks) {
    int k = 64 + ks * 32 + l4 * 8;
    int hh = k / 40, d = k - hh * 40;
    hB[0 + ks] = *(const vh8*)(hohm + ((size_t)(bb0 * 8 + hh) * 4096 + ii0) * 40 + d);
    hB[2 + ks] = *(const vh8*)(hohm + ((size_t)(bb1 * 8 + hh) * 4096 + ii1) * 40 + d);
  }
  WAITCNT9();
  SBAR();

#pragma unroll
  for (int kc = 0; kc < 5; ++kc) {
    char* BsCur = (char*)Bs[kc & 1];
    vh8* cur = (kc & 1) ? hB : hA;
#pragma unroll
    for (int s = 0; s < 2; ++s) {
#pragma unroll
      for (int ks = 0; ks < 2; ++ks) {
#pragma unroll
        for (int nt = 0; nt < 10; ++nt) {
          int n = cg * 160 + nt * 16 + l15;
          unsigned byte = (unsigned)(n * 128 + (ks * 32 + l4 * 8) * 2) ^ swzB(n);
          vh8 bv = *(const vh8*)(BsCur + byte);
          acc[s][nt] = __builtin_amdgcn_mfma_f32_16x16x32_f16(cur[s * 2 + ks], bv, acc[s][nt], 0, 0, 0);
        }
      }
    }
    if (kc < 4) {
      SBAR();
      if (kc < 3) {
        int k0n = (kc + 2) * 64;
#pragma unroll
        for (int p = 0; p < 5; ++p) {
          int idx = t + p * 512;
          int n = idx >> 3, c8 = idx & 7;
          glds16(Bt + (size_t)n * 320 + k0n + ((c8 ^ (n & 7)) << 3),
                 BsCur + (size_t)(p * 512 + wbase) * 16);
        }
#pragma unroll
        for (int ks = 0; ks < 2; ++ks) {
          int k = k0n + ks * 32 + l4 * 8;
          int hh = k / 40, d = k - hh * 40;
          cur[0 + ks] = *(const vh8*)(hohm + ((size_t)(bb0 * 8 + hh) * 4096 + ii0) * 40 + d);
          cur[2 + ks] = *(const vh8*)(hohm + ((size_t)(bb1 * 8 + hh) * 4096 + ii1) * 40 + d);
        }
        WAITCNT9();
      } else {
        WAITCNT0();
      }
      SBAR();
    }
  }
#pragma unroll
  for (int s = 0; s < 2; ++s)
#pragma unroll
    for (int nt = 0; nt < 10; ++nt) {
      int n = cg * 160 + nt * 16 + l15;
      float bias_v = bias[n];
#pragma unroll
      for (int r = 0; r < 4; ++r) {
        int m = m0 + s * 64 + rg * 16 + l4 * 4 + r;
        out[(size_t)m * 320 + n] = acc[s][nt][r] + bias_v;
      }
    }
}

// ---------------------------------------------------------------------------
// Progress classifier
// ---------------------------------------------------------------------------
__global__ __launch_bounds__(256) void classifier_kernel(
    const float* __restrict__ progress,
    const float* __restrict__ emb1, const float* __restrict__ emb2,
    const float* __restrict__ Wc1, const float* __restrict__ bc1,
    const float* __restrict__ Wc2, const float* __restrict__ bc2,
    float* __restrict__ pcb)
{
  __shared__ float g[512];
  __shared__ float h1[512];
  __shared__ float lg[16];
  const int b = blockIdx.x;
  const int t = threadIdx.x;

  float pr = progress[b];
  int xstep = (int)rintf(pr * 1000.0f);
  if (xstep > 999) xstep = 999;
  int a = xstep / 20;
  int r = xstep - a * 20;

  for (int d = t; d < 512; d += 256) {
    float e = emb1[a * 512 + d] + emb2[r * 512 + d];
    g[d] = gelu_exact(e);
  }
  __syncthreads();
  for (int n = t; n < 512; n += 256) {
    float acc = bc1[n];
    for (int d = 0; d < 512; ++d) acc = fmaf(g[d], Wc1[d * 512 + n], acc);
    h1[n] = gelu_exact(acc);
  }
  __syncthreads();
  if (t < 16) {
    float acc = bc2[t];
    for (int d = 0; d < 512; ++d) acc = fmaf(h1[d], Wc2[d * 16 + t], acc);
    lg[t] = acc;
  }
  __syncthreads();
  if (t < 8) {
    float a0 = lg[2 * t], a1 = lg[2 * t + 1];
    float mx = fmaxf(a0, a1);
    float e0 = __expf(a0 - mx), e1 = __expf(a1 - mx);
    float inv = 1.0f / (e0 + e1);
    pcb[(b * 8 + t) * 2 + 0] = e0 * inv;
    pcb[(b * 8 + t) * 2 + 1] = e1 * inv;
  }
}

__global__ __launch_bounds__(256) void finalize_kernel(
    const double* __restrict__ partials, const int* __restrict__ ctypes,
    float* __restrict__ ssb)
{
  __shared__ double rs[256];
  __shared__ double rs2[256];
  __shared__ int rc[256];
  const int t = threadIdx.x;
  double S = 0.0, S2 = 0.0;
#pragma unroll
  for (int p = 0; p < 16; ++p) {
    int idx = t + p * 256;
    S += partials[2 * idx + 0];
    S2 += partials[2 * idx + 1];
  }
  int c = 0;
#pragma unroll
  for (int p = 0; p < 5; ++p) {
    int idx = t + p * 256;
    if (idx < 1232) c += (ctypes[idx] >= 2) ? 1 : 0;
  }
  rs[t] = S; rs2[t] = S2; rc[t] = c;
  __syncthreads();
  for (int off = 128; off > 0; off >>= 1) {
    if (t < off) { rs[t] += rs[t + off]; rs2[t] += rs2[t + off]; rc[t] += rc[t + off]; }
    __syncthreads();
  }
  if (t == 0) {
    double n = (double)rc[0] * 8.0 * 4096.0;
    double mean = rs[0] / n;
    double var = (rs2[0] - n * mean * mean) / (n - 1.0);
    ssb[0] = (float)sqrt(var > 0.0 ? var : 0.0);
  }
}

// ---------------------------------------------------------------------------
// lmask precompute: packed bits lmp[row][qd], qd=j&3, bit m=j>>2.
// ---------------------------------------------------------------------------
__global__ __launch_bounds__(256) void lmask_kernel(
    const float* __restrict__ cam, const int* __restrict__ ctypes,
    const float* __restrict__ ssb, const float* __restrict__ strengthp,
    unsigned* __restrict__ lmp)
{
  __shared__ float camt[64 * 81];
  __shared__ unsigned char gmv[96];
  __shared__ unsigned char m2v[96];
  const int t = threadIdx.x;
  const int it = blockIdx.x, b = blockIdx.y;
  const int i0 = it * 64;

  if (t < 96) {
    int j = t;
    int ct = (j < 77) ? ctypes[b * 77 + j] : -1;
    gmv[j] = (j < 77 && ct >= 0 && ct < 2) ? 1 : 0;
    m2v[j] = (j < 77 && ct >= 2) ? 1 : 0;
  }
#pragma unroll
  for (int p = 0; p < 20; ++p) {
    int idx = t + p * 256;
    int row = idx / 80;
    int j = idx - row * 80;
    camt[row * 81 + j] = (j < 77) ? cam[((size_t)b * 4096 + i0 + row) * 77 + j] : 0.f;
  }
  __syncthreads();

  const float ss = ssb[0];
  const float st = strengthp[0];
  int row = t >> 2, qd = t & 3;
  float wfv[20];
  float wmax = 0.f, wsum = 0.f;
#pragma unroll
  for (int m = 0; m < 20; ++m) {
    int j = qd + 4 * m;
    float wf = 0.f;
    if (j < 77 && m2v[j]) wf = (camt[row * 81 + j] * ss) * st;   // ref assoc order
    wfv[m] = wf;
    wmax = fmaxf(wmax, wf);
    wsum += wf;
  }
  wmax = fmaxf(wmax, __shfl_xor(wmax, 1));
  wmax = fmaxf(wmax, __shfl_xor(wmax, 2));
  wsum += __shfl_xor(wsum, 1);
  wsum += __shfl_xor(wsum, 2);
  float thr = fmaxf(wmax, 0.001f) - 0.0001f;
  bool ug = (wsum == 0.f);
  unsigned wbits = 0u;
#pragma unroll
  for (int m = 0; m < 20; ++m) {
    int j = qd + 4 * m;
    bool lv = (wfv[m] >= thr) || (ug && (j < 77) && gmv[j]);
    if (lv) wbits |= (1u << m);
  }
  lmp[((size_t)b * 4096 + i0 + row) * 4 + qd] = wbits;
}

// ---------------------------------------------------------------------------
// Fused attention: grid (64,16,8), 256 thr. Native __expf softmax.
// ---------------------------------------------------------------------------
__global__ __launch_bounds__(256) void attn_kernel(
    const _Float16* __restrict__ qhm, const _Float16* __restrict__ kf,
    const unsigned* __restrict__ vTg32, const int* __restrict__ ctypes,
    const float* __restrict__ pcb, const unsigned* __restrict__ lmp,
    _Float16* __restrict__ hohm)
{
  __shared__ _Float16 vT[48 * 128];        // [d][j] pitch 256B, XOR swzA(d)
  __shared__ _Float16 attnbuf[64 * 128];   // [row][j] pitch 256B, XOR swzA(row)
  __shared__ __align__(16) _Float16 qt[64 * 40];  // 5120B, reused for PV out
  __shared__ unsigned lmw[256];
  __shared__ float gbf[96];
  __shared__ float nbf[96];

  const int t = threadIdx.x, lane = t & 63, wave = t >> 6;
  const int it = blockIdx.x, b = blockIdx.y, h = blockIdx.z;
  const int i0 = it * 64;
  const int l15 = lane & 15, l4 = lane >> 4;

  if (t < 96) {
    int j = t;
    bool valid = (j < 77);
    int ct = valid ? ctypes[b * 77 + j] : -1;
    bool gm = valid && ct >= 0 && ct < 2;
    gbf[j] = gm ? 0.f : (valid ? NEGBIG : -INFF);
    nbf[j] = valid ? NEGBIG : -INFF;
  }
  lmw[t] = lmp[((size_t)b * 4096 + i0) * 4 + t];

  const _Float16* qsrc = qhm + ((size_t)(b * 8 + h) * 4096 + i0) * 40;
  glds16(qsrc + t * 8, (char*)qt + t * 16);
  if (t < 64) glds16(qsrc + (256 + t) * 8, (char*)qt + (256 + t) * 16);

  {
    const unsigned* src0 = vTg32 + (size_t)(b * 8 + h) * 3072;
#pragma unroll
    for (int p = 0; p < 3; ++p) {
      int idx = t + p * 256;
      glds16(src0 + idx * 4, (char*)vT + (size_t)(p * 256 + (t & ~63)) * 16);
    }
  }
#pragma unroll
  for (int p = 0; p < 2; ++p) {
    int idx = t + p * 256;
    int row = idx >> 3, c = idx & 7;
    unsigned byte = (unsigned)(row * 256 + 160 + c * 4) ^ swzA(row);
    *(unsigned*)((char*)attnbuf + byte) = 0u;
  }

  vh8 k0v[5], k1v[5];
#pragma unroll
  for (int jt = 0; jt < 5; ++jt) {
    int j = jt * 16 + l15;
    k0v[jt] = h8zero(); k1v[jt] = h8zero();
    if (j < 77) {
      const _Float16* kp = kf + (size_t)(b * 77 + j) * 640 + h * 40;
      k0v[jt] = *(const vh8*)(kp + l4 * 8);
      if (l4 == 0) k1v[jt] = *(const vh8*)(kp + 32);
    }
  }

  __syncthreads();

  const int myrow = wave * 16 + l15;
  vh8 qf0 = *(const vh8*)((const char*)qt + myrow * 80 + l4 * 16);
  vh8 qf1 = h8zero();
  if (l4 == 0) qf1 = *(const vh8*)((const char*)qt + myrow * 80 + 64);

  vf4 sacc[5];
#pragma unroll
  for (int jt = 0; jt < 5; ++jt) sacc[jt] = f4zero();
#pragma unroll
  for (int jt = 0; jt < 5; ++jt) {
    sacc[jt] = __builtin_amdgcn_mfma_f32_16x16x32_f16(k0v[jt], qf0, sacc[jt], 0, 0, 0);
    sacc[jt] = __builtin_amdgcn_mfma_f32_16x16x32_f16(k1v[jt], qf1, sacc[jt], 0, 0, 0);
  }

  const float pc0 = pcb[(b * 8 + h) * 2 + 0];
  const float pc1 = pcb[(b * 8 + h) * 2 + 1];
  unsigned wbits[4];
#pragma unroll
  for (int r = 0; r < 4; ++r) wbits[r] = lmw[myrow * 4 + r];

  float gv[5][4], lv[5][4];
  float mg = -INFF, ml = -INFF;
#pragma unroll
  for (int jt = 0; jt < 5; ++jt) {
    int jbase = jt * 16 + l4 * 4;
    float4 gb4 = *(const float4*)&gbf[jbase];
    float4 nb4 = *(const float4*)&nbf[jbase];
    const float* gbp = (const float*)&gb4;
    const float* nbp = (const float*)&nb4;
#pragma unroll
    for (int r = 0; r < 4; ++r) {
      float sv = sacc[jt][r];
      float g = fmaf(sv, SCALE_F, gbp[r]);
      unsigned bit = (wbits[r] >> (jt * 4 + l4)) & 1u;
      float l = fmaf(sv, SCALE_F, bit ? 0.f : nbp[r]);
      gv[jt][r] = g; lv[jt][r] = l;
      mg = fmaxf(mg, g); ml = fmaxf(ml, l);
    }
  }
  mg = fmaxf(mg, __shfl_xor(mg, 16)); mg = fmaxf(mg, __shfl_xor(mg, 32));
  ml = fmaxf(ml, __shfl_xor(ml, 16)); ml = fmaxf(ml, __shfl_xor(ml, 32));
  float sG = 0.f, sL = 0.f;
#pragma unroll
  for (int jt = 0; jt < 5; ++jt)
#pragma unroll
    for (int r = 0; r < 4; ++r) {
      float eg = __expf(gv[jt][r] - mg);
      float el = __expf(lv[jt][r] - ml);
      gv[jt][r] = eg; lv[jt][r] = el;
      sG += eg; sL += el;
    }
  sG += __shfl_xor(sG, 16); sG += __shfl_xor(sG, 32);
  sL += __shfl_xor(sL, 16); sL += __shfl_xor(sL, 32);
  float rG = pc0 / sG, rL = pc1 / sL;
  {
    unsigned swz = swzA(myrow);
    unsigned rowbase = (unsigned)(myrow * 256);
#pragma unroll
    for (int jt = 0; jt < 5; ++jt) {
      vh4 w;
#pragma unroll
      for (int r = 0; r < 4; ++r)
        w[r] = (_Float16)fmaf(gv[jt][r], rG, lv[jt][r] * rL);
      unsigned byte = (rowbase + (unsigned)((jt * 16 + l4 * 4) * 2)) ^ swz;
      *(vh4*)((char*)attnbuf + byte) = w;
    }
  }
  __syncthreads();

  vf4 oacc[3];
#pragma unroll
  for (int nt = 0; nt < 3; ++nt) oacc[nt] = f4zero();
#pragma unroll
  for (int ks = 0; ks < 3; ++ks) {
    int arow = wave * 16 + l15;
    unsigned abyte = (unsigned)(arow * 256 + (ks * 32 + l4 * 8) * 2) ^ swzA(arow);
    vh8 pa = *(const vh8*)((const char*)attnbuf + abyte);
#pragma unroll
    for (int nt = 0; nt < 3; ++nt) {
      int n = nt * 16 + l15;
      unsigned byte = (unsigned)(n * 256 + (ks * 32 + l4 * 8) * 2) ^ swzA(n);
      vh8 vb = *(const vh8*)((const char*)vT + byte);
      oacc[nt] = __builtin_amdgcn_mfma_f32_16x16x32_f16(pa, vb, oacc[nt], 0, 0, 0);
    }
  }
#pragma unroll
  for (int nt = 0; nt < 3; ++nt) {
    int d = nt * 16 + l15;
    if (d < 40) {
#pragma unroll
      for (int r = 0; r < 4; ++r) {
        int m = wave * 16 + l4 * 4 + r;
        qt[m * 40 + d] = (_Float16)oacc[nt][r];
      }
    }
  }
  __syncthreads();

  _Float16* obase = hohm + ((size_t)(b * 8 + h) * 4096 + i0) * 40;
  {
    vh8 v = *(const vh8*)((const char*)qt + t * 16);
    *(vh8*)(obase + t * 8) = v;
  }
  if (t < 64) {
    vh8 v = *(const vh8*)((const char*)qt + (256 + t) * 16);
    *(vh8*)(obase + (256 + t) * 8) = v;
  }
}

// ---------------------------------------------------------------------------
extern "C" void kernel_launch(void* const* d_in, const int* in_sizes, int n_in,
                              void* d_out, int out_size, void* d_ws, size_t ws_size,
                              hipStream_t stream)
{
  const float* x        = (const float*)d_in[0];
  const float* embs     = (const float*)d_in[1];
  const float* cam      = (const float*)d_in[2];
  const float* progress = (const float*)d_in[3];
  const float* strength = (const float*)d_in[4];
  const float* Wq       = (const float*)d_in[5];
  const float* Wk       = (const float*)d_in[6];
  const float* Wv       = (const float*)d_in[7];
  const float* Wo       = (const float*)d_in[8];
  const float* bo       = (const float*)d_in[9];
  const float* emb1     = (const float*)d_in[10];
  const float* emb2     = (const float*)d_in[11];
  const float* Wc1      = (const float*)d_in[12];
  const float* bc1      = (const float*)d_in[13];
  const float* Wc2      = (const float*)d_in[14];
  const float* bc2      = (const float*)d_in[15];
  const int*   ctypes   = (const int*)d_in[16];

  char* w = (char*)d_ws;
  auto alloc = [&](size_t bytes) { char* p = w; w += (bytes + 255) & ~(size_t)255; return p; };
  _Float16* qhm   = (_Float16*)alloc(65536ull * 320 * 2);   // 40 MiB head-major
  _Float16* hohm  = (_Float16*)alloc(65536ull * 320 * 2);   // 40 MiB head-major
  _Float16* kvb   = (_Float16*)alloc(1232ull * 640 * 2);    // 1.5 MiB
  unsigned* vTg   = (unsigned*)alloc(128ull * 3072 * 4);    // 1.5 MiB
  _Float16* WqT   = (_Float16*)alloc(320ull * 320 * 2);
  _Float16* WkvT  = (_Float16*)alloc(640ull * 768 * 2);
  _Float16* WoT   = (_Float16*)alloc(320ull * 320 * 2);
  unsigned* lmp   = (unsigned*)alloc(65536ull * 4 * 4);     // 1 MiB
  float*    pcb   = (float*)alloc(256 * 4);
  double*   part  = (double*)alloc(4096ull * 2 * 8);        // 64 KiB
  float*    ssb   = (float*)alloc(256);

  transpose_kernel<<<680, 256, 0, stream>>>(Wq, Wk, Wv, Wo, WqT, WkvT, WoT);
  classifier_kernel<<<16, 256, 0, stream>>>(progress, emb1, emb2, Wc1, bc1, Wc2, bc2, pcb);
  kv_gemm_kernel<<<dim3(20, 4), 256, 0, stream>>>(embs, WkvT, kvb);
  vtrans_kernel<<<dim3(16, 8), 256, 0, stream>>>(kvb + 320, vTg);
  qproj_kernel<<<512, 512, 0, stream>>>(x, WqT, kvb, ctypes, qhm, part);
  finalize_kernel<<<1, 256, 0, stream>>>(part, ctypes, ssb);
  lmask_kernel<<<dim3(64, 16), 256, 0, stream>>>(cam, ctypes, ssb, strength, lmp);
  attn_kernel<<<dim3(64, 16, 8), 256, 0, stream>>>(qhm, kvb, vTg, ctypes, pcb, lmp, hohm);
  oproj_kernel<<<512, 512, 0, stream>>>(hohm, WoT, bo, (float*)d_out);
}

// Round 18
// 243.335 us; speedup vs baseline: 1.0348x; 1.0348x over previous
//
#include <hip/hip_runtime.h>

// ---------------------------------------------------------------------------
// CustomCrossAttentionMinimal on MI355X (gfx950)
// b=16, i=4096, j=77, qd=320, cd=768, H=8, DH=40, inner=320
// Layouts: qhm/hohm are head-major fp16 [b][h][4096][40]
// ---------------------------------------------------------------------------

typedef _Float16 vh8 __attribute__((ext_vector_type(8)));
typedef _Float16 vh4 __attribute__((ext_vector_type(4)));
typedef float    vf4 __attribute__((ext_vector_type(4)));

#define NEGBIG  (-3.4028235e38f)
#define SCALE_F 0.15811388300841897f     // 40^-0.5
#define INFF    (__builtin_inff())

#define WAITCNT9() do { asm volatile("s_waitcnt vmcnt(9)" ::: "memory"); __builtin_amdgcn_sched_barrier(0); } while (0)
#define WAITCNT0() do { asm volatile("s_waitcnt vmcnt(0)" ::: "memory"); __builtin_amdgcn_sched_barrier(0); } while (0)
#define SBAR()     __builtin_amdgcn_s_barrier()

__device__ __forceinline__ vh8 h8zero() {
  vh8 v;
#pragma unroll
  for (int i = 0; i < 8; ++i) v[i] = (_Float16)0.f;
  return v;
}
__device__ __forceinline__ vf4 f4zero() {
  vf4 v;
#pragma unroll
  for (int i = 0; i < 4; ++i) v[i] = 0.f;
  return v;
}
__device__ __forceinline__ float gelu_exact(float x) {
  return 0.5f * x * (1.0f + erff(x * 0.70710678118654752f));
}
__device__ __forceinline__ unsigned swzA(int row) {
  return (unsigned)(((row & 7) << 4) ^ (((row >> 3) & 1) << 5));
}
__device__ __forceinline__ unsigned swzB(int row) {
  return (unsigned)((row & 7) << 4);
}
__device__ __forceinline__ void glds16(const void* g, void* l) {
  __builtin_amdgcn_global_load_lds((const __attribute__((address_space(1))) unsigned*)g,
                                   (__attribute__((address_space(3))) unsigned*)l, 16, 0, 0);
}

// ---------------------------------------------------------------------------
// prep kernel: blocks 0..679 = tiled weight transpose (fp32 -> fp16 [N][K]);
// blocks 680..695 = progress classifier (b = blockIdx - 680). 256 thr.
// ---------------------------------------------------------------------------
__global__ __launch_bounds__(256) void prep_kernel(
    const float* __restrict__ Wq, const float* __restrict__ Wk,
    const float* __restrict__ Wv, const float* __restrict__ Wo,
    _Float16* __restrict__ WqT, _Float16* __restrict__ WkvT, _Float16* __restrict__ WoT,
    const float* __restrict__ progress,
    const float* __restrict__ emb1, const float* __restrict__ emb2,
    const float* __restrict__ Wc1, const float* __restrict__ bc1,
    const float* __restrict__ Wc2, const float* __restrict__ bc2,
    float* __restrict__ pcb)
{
  if (blockIdx.x < 680) {
    __shared__ float ts[32][33];
    int tile = blockIdx.x;
    const float* src; _Float16* dst; int dstK, rowOff;
    if (tile < 100)      { src = Wq; dst = WqT;  dstK = 320; rowOff = 0; }
    else if (tile < 340) { src = Wk; dst = WkvT; dstK = 768; rowOff = 0;   tile -= 100; }
    else if (tile < 580) { src = Wv; dst = WkvT; dstK = 768; rowOff = 320; tile -= 340; }
    else                 { src = Wo; dst = WoT;  dstK = 320; rowOff = 0;   tile -= 580; }
    int kb = tile / 10, nb = tile - kb * 10;
    int k0 = kb * 32, n0 = nb * 32;
    int r = threadIdx.x >> 5, c = threadIdx.x & 31;
#pragma unroll
    for (int p = 0; p < 4; ++p)
      ts[r + p * 8][c] = src[(size_t)(k0 + r + p * 8) * 320 + n0 + c];
    __syncthreads();
#pragma unroll
    for (int p = 0; p < 4; ++p)
      dst[(size_t)(rowOff + n0 + r + p * 8) * dstK + k0 + c] = (_Float16)ts[c][r + p * 8];
    return;
  }
  // classifier path
  {
    __shared__ float g[512];
    __shared__ float h1[512];
    __shared__ float lg[16];
    const int b = blockIdx.x - 680;
    const int t = threadIdx.x;

    float pr = progress[b];
    int xstep = (int)rintf(pr * 1000.0f);
    if (xstep > 999) xstep = 999;
    int a = xstep / 20;
    int r = xstep - a * 20;

    for (int d = t; d < 512; d += 256) {
      float e = emb1[a * 512 + d] + emb2[r * 512 + d];
      g[d] = gelu_exact(e);
    }
    __syncthreads();
    for (int n = t; n < 512; n += 256) {
      float acc = bc1[n];
      for (int d = 0; d < 512; ++d) acc = fmaf(g[d], Wc1[d * 512 + n], acc);
      h1[n] = gelu_exact(acc);
    }
    __syncthreads();
    if (t < 16) {
      float acc = bc2[t];
      for (int d = 0; d < 512; ++d) acc = fmaf(h1[d], Wc2[d * 16 + t], acc);
      lg[t] = acc;
    }
    __syncthreads();
    if (t < 8) {
      float a0 = lg[2 * t], a1 = lg[2 * t + 1];
      float mx = fmaxf(a0, a1);
      float e0 = __expf(a0 - mx), e1 = __expf(a1 - mx);
      float inv = 1.0f / (e0 + e1);
      pcb[(b * 8 + t) * 2 + 0] = e0 * inv;
      pcb[(b * 8 + t) * 2 + 1] = e1 * inv;
    }
  }
}

// ---------------------------------------------------------------------------
// KV GEMM (barrier-free): C[1232,640] = embs[1232,768] @ WkvT[640,768]^T
// ---------------------------------------------------------------------------
__global__ __launch_bounds__(256) void kv_gemm_kernel(
    const float* __restrict__ Ap, const _Float16* __restrict__ Bt,
    _Float16* __restrict__ Cp)
{
  const int t = threadIdx.x, lane = t & 63, wave = t >> 6;
  const int m0 = blockIdx.x * 64;
  const int n0 = blockIdx.y * 160;
  const int l15 = lane & 15, l4 = lane >> 4;
  const int rg = wave >> 1, cg = wave & 1;

  vf4 acc[2][5];
#pragma unroll
  for (int a = 0; a < 2; ++a)
#pragma unroll
    for (int bq = 0; bq < 5; ++bq) acc[a][bq] = f4zero();

#pragma unroll 2
  for (int kk = 0; kk < 24; ++kk) {
    int k = kk * 32 + l4 * 8;
    vh8 av[2];
#pragma unroll
    for (int mt = 0; mt < 2; ++mt) {
      int row = m0 + rg * 32 + mt * 16 + l15;
      av[mt] = h8zero();
      if (row < 1232) {
        const float* ap = Ap + (size_t)row * 768 + k;
        float4 f0 = *(const float4*)ap;
        float4 f1 = *(const float4*)(ap + 4);
        vh8 hv;
        hv[0] = (_Float16)f0.x; hv[1] = (_Float16)f0.y; hv[2] = (_Float16)f0.z; hv[3] = (_Float16)f0.w;
        hv[4] = (_Float16)f1.x; hv[5] = (_Float16)f1.y; hv[6] = (_Float16)f1.z; hv[7] = (_Float16)f1.w;
        av[mt] = hv;
      }
    }
#pragma unroll
    for (int nt = 0; nt < 5; ++nt) {
      int n = n0 + cg * 80 + nt * 16 + l15;
      vh8 bv = *(const vh8*)(Bt + (size_t)n * 768 + k);
      acc[0][nt] = __builtin_amdgcn_mfma_f32_16x16x32_f16(av[0], bv, acc[0][nt], 0, 0, 0);
      acc[1][nt] = __builtin_amdgcn_mfma_f32_16x16x32_f16(av[1], bv, acc[1][nt], 0, 0, 0);
    }
  }
#pragma unroll
  for (int mt = 0; mt < 2; ++mt)
#pragma unroll
    for (int nt = 0; nt < 5; ++nt) {
      int n = n0 + cg * 80 + nt * 16 + l15;
#pragma unroll
      for (int r = 0; r < 4; ++r) {
        int m = m0 + rg * 32 + mt * 16 + l4 * 4 + r;
        if (m < 1232) Cp[(size_t)m * 640 + n] = (_Float16)acc[mt][nt][r];
      }
    }
}

// ---------------------------------------------------------------------------
// Q projection + fused std + (blocks >=512) V^T pre-swizzle.
// 512 thr, 8 waves, BM=128 (2 subtiles of 64 rows). Counted-vmcnt 2-deep.
// ---------------------------------------------------------------------------
__global__ __launch_bounds__(512) void qproj_kernel(
    const float* __restrict__ x, const _Float16* __restrict__ Bt,
    const _Float16* __restrict__ kf, const int* __restrict__ ctypes,
    _Float16* __restrict__ qhm, double* __restrict__ partials,
    const _Float16* __restrict__ vf, unsigned* __restrict__ vTg32)
{
  __shared__ __align__(16) char smem[81920];   // buf0 @0, buf1 @40960; buf0 reused for re-tile
  const int t = threadIdx.x, lane = t & 63, wave = t >> 6;

  if (blockIdx.x >= 512) {
    // vtrans path: vb in 0..127 -> (b, h)
    int vb = blockIdx.x - 512;
    int b = vb >> 3, h = vb & 7;
    unsigned* out = vTg32 + (size_t)(b * 8 + h) * 3072;
#pragma unroll
    for (int p = 0; p < 6; ++p) {
      int idx = t + p * 512;            // u32 index 0..3071
      int d = idx >> 6;
      int u = idx & 63;
      int c = u >> 2, pr = u & 3;
      int sd = (int)(swzA(d) >> 4);
      int j0 = ((c ^ sd) << 3) + pr * 2;
      unsigned lo = 0, hi = 0;
      if (d < 40) {
        if (j0 < 77)     lo = *(const unsigned short*)(vf + (size_t)(b * 77 + j0) * 640 + h * 40 + d);
        if (j0 + 1 < 77) hi = *(const unsigned short*)(vf + (size_t)(b * 77 + j0 + 1) * 640 + h * 40 + d);
      }
      out[idx] = lo | (hi << 16);
    }
    return;
  }

  const int m0 = blockIdx.x * 128;
  const int l15 = lane & 15, l4 = lane >> 4;
  const int wbase = t & ~63;
  const int rg = wave >> 1, cg = wave & 1;          // rg 0..3, cg 0..1
  const float* arow0 = x + (size_t)(m0 + rg * 16 + l15) * 320 + l4 * 8;        // subtile 0
  const float* arow1 = x + (size_t)(m0 + 64 + rg * 16 + l15) * 320 + l4 * 8;   // subtile 1

  vf4 acc[2][10];
#pragma unroll
  for (int s = 0; s < 2; ++s)
#pragma unroll
    for (int bq = 0; bq < 10; ++bq) acc[s][bq] = f4zero();

  float4 fA[8], fB[8];   // [s*4 + ks*2 + half]

  // ---- prologue: group(0) = B(0)+A(0); group(1) = B(1)+A(1) ----
#pragma unroll
  for (int p = 0; p < 5; ++p) {
    int idx = t + p * 512;
    int n = idx >> 3, c8 = idx & 7;
    glds16(Bt + (size_t)n * 320 + 0 + ((c8 ^ (n & 7)) << 3),
           smem + (size_t)(p * 512 + wbase) * 16);
  }
#pragma unroll
  for (int ks = 0; ks < 2; ++ks) {
    fA[0 + ks * 2 + 0] = *(const float4*)(arow0 + ks * 32);
    fA[0 + ks * 2 + 1] = *(const float4*)(arow0 + ks * 32 + 4);
    fA[4 + ks * 2 + 0] = *(const float4*)(arow1 + ks * 32);
    fA[4 + ks * 2 + 1] = *(const float4*)(arow1 + ks * 32 + 4);
  }
  __builtin_amdgcn_sched_barrier(0);   // group(0) fully issued before group(1)
#pragma unroll
  for (int p = 0; p < 5; ++p) {
    int idx = t + p * 512;
    int n = idx >> 3, c8 = idx & 7;
    glds16(Bt + (size_t)n * 320 + 64 + ((c8 ^ (n & 7)) << 3),
           smem + 40960 + (size_t)(p * 512 + wbase) * 16);
  }
#pragma unroll
  for (int ks = 0; ks < 2; ++ks) {
    fB[0 + ks * 2 + 0] = *(const float4*)(arow0 + 64 + ks * 32);
    fB[0 + ks * 2 + 1] = *(const float4*)(arow0 + 64 + ks * 32 + 4);
    fB[4 + ks * 2 + 0] = *(const float4*)(arow1 + 64 + ks * 32);
    fB[4 + ks * 2 + 1] = *(const float4*)(arow1 + 64 + ks * 32 + 4);
  }
  WAITCNT9();        // group(0) complete; group(1) may remain in flight
  SBAR();

#pragma unroll
  for (int kc = 0; kc < 5; ++kc) {
    char* BsCur = smem + (size_t)(kc & 1) * 40960;
    float4* cur = (kc & 1) ? fB : fA;
    // compute tile kc
#pragma unroll
    for (int s = 0; s < 2; ++s) {
#pragma unroll
      for (int ks = 0; ks < 2; ++ks) {
        float4 f0 = cur[s * 4 + ks * 2 + 0];
        float4 f1 = cur[s * 4 + ks * 2 + 1];
        vh8 av;
        av[0] = (_Float16)f0.x; av[1] = (_Float16)f0.y; av[2] = (_Float16)f0.z; av[3] = (_Float16)f0.w;
        av[4] = (_Float16)f1.x; av[5] = (_Float16)f1.y; av[6] = (_Float16)f1.z; av[7] = (_Float16)f1.w;
#pragma unroll
        for (int nt = 0; nt < 10; ++nt) {
          int n = cg * 160 + nt * 16 + l15;
          unsigned byte = (unsigned)(n * 128 + (ks * 32 + l4 * 8) * 2) ^ swzB(n);
          vh8 bv = *(const vh8*)(BsCur + byte);
          acc[s][nt] = __builtin_amdgcn_mfma_f32_16x16x32_f16(av, bv, acc[s][nt], 0, 0, 0);
        }
      }
    }
    if (kc < 4) {
      SBAR();                      // all waves done reading buf[kc&1]
      if (kc < 3) {
        int k0n = (kc + 2) * 64;   // stage group(kc+2) into buf[kc&1]
#pragma unroll
        for (int p = 0; p < 5; ++p) {
          int idx = t + p * 512;
          int n = idx >> 3, c8 = idx & 7;
          glds16(Bt + (size_t)n * 320 + k0n + ((c8 ^ (n & 7)) << 3),
                 BsCur + (size_t)(p * 512 + wbase) * 16);
        }
#pragma unroll
        for (int ks = 0; ks < 2; ++ks) {
          cur[0 + ks * 2 + 0] = *(const float4*)(arow0 + k0n + ks * 32);
          cur[0 + ks * 2 + 1] = *(const float4*)(arow0 + k0n + ks * 32 + 4);
          cur[4 + ks * 2 + 0] = *(const float4*)(arow1 + k0n + ks * 32);
          cur[4 + ks * 2 + 1] = *(const float4*)(arow1 + k0n + ks * 32 + 4);
        }
        WAITCNT9();                // group(kc+1) complete
      } else {
        WAITCNT0();                // kc==3: group(4) complete
      }
      SBAR();                      // buf[(kc+1)&1] visible to all waves
    }
  }
  __syncthreads();                 // protect buf0 before epilogue reuse

  // per-subtile epilogue: re-tile -> scatter -> fused std
  double S = 0.0, S2 = 0.0;
  const int b = m0 >> 12;
  const int h = wave;
#pragma unroll
  for (int s = 0; s < 2; ++s) {
#pragma unroll
    for (int nt = 0; nt < 10; ++nt) {
      int col = cg * 160 + nt * 16 + l15;
#pragma unroll
      for (int r = 0; r < 4; ++r) {
        int lr = rg * 16 + l4 * 4 + r;
        unsigned byte = (unsigned)(lr * 640 + col * 2) ^ swzB(lr);
        *(_Float16*)(smem + byte) = (_Float16)acc[s][nt][r];
      }
    }
    __syncthreads();
#pragma unroll
    for (int p = 0; p < 5; ++p) {
      int idx = t + p * 512;               // 0..2559 = 64 rows x 8 heads x 5 chunks
      int hh = idx / 320;
      int rem = idx - hh * 320;
      int lrow = rem / 5;
      int c = rem - lrow * 5;
      unsigned sb = (unsigned)(lrow * 640 + hh * 80 + c * 16) ^ swzB(lrow);
      vh8 v = *(const vh8*)(smem + sb);
      int gi = m0 + s * 64 + lrow;
      int bb = gi >> 12, ii = gi & 4095;
      *(vh8*)(qhm + ((size_t)(bb * 8 + hh) * 4096 + ii) * 40 + c * 8) = v;
    }
    {
      vh8 a0v[4], a1v[4];
#pragma unroll
      for (int mt = 0; mt < 4; ++mt) {
        int qrow = mt * 16 + l15;
        unsigned b0 = (unsigned)(qrow * 640 + (h * 40 + l4 * 8) * 2) ^ swzB(qrow);
        a0v[mt] = *(const vh8*)(smem + b0);
        a1v[mt] = h8zero();
        if (l4 == 0) {
          unsigned b1 = (unsigned)(qrow * 640 + (h * 40 + 32) * 2) ^ swzB(qrow);
          a1v[mt] = *(const vh8*)(smem + b1);
        }
      }
#pragma unroll
      for (int jt = 0; jt < 5; ++jt) {
        int j = jt * 16 + l15;
        bool valid = (j < 77);
        vh8 b0 = h8zero(), b1 = h8zero();
        int ctj = -1;
        if (valid) {
          const _Float16* kp = kf + (size_t)(b * 77 + j) * 640 + h * 40;
          b0 = *(const vh8*)(kp + l4 * 8);
          if (l4 == 0) b1 = *(const vh8*)(kp + 32);
          ctj = ctypes[b * 77 + j];
        }
#pragma unroll
        for (int mt = 0; mt < 4; ++mt) {
          vf4 sv4 = f4zero();
          sv4 = __builtin_amdgcn_mfma_f32_16x16x32_f16(a0v[mt], b0, sv4, 0, 0, 0);
          sv4 = __builtin_amdgcn_mfma_f32_16x16x32_f16(a1v[mt], b1, sv4, 0, 0, 0);
          if (ctj >= 2) {
#pragma unroll
            for (int r = 0; r < 4; ++r) {
              double sv = (double)sv4[r];
              S += sv; S2 += sv * sv;
            }
          }
        }
      }
    }
    __syncthreads();
  }
#pragma unroll
  for (int off = 32; off > 0; off >>= 1) {
    S += __shfl_xor(S, off);
    S2 += __shfl_xor(S2, off);
  }
  if (lane == 0) {
    int idx = blockIdx.x * 8 + wave;
    partials[2 * idx + 0] = S;
    partials[2 * idx + 1] = S2;
  }
}

// ---------------------------------------------------------------------------
// O projection: 512 thr, 8 waves, BM=128 (2 subtiles). Counted-vmcnt 2-deep.
// ---------------------------------------------------------------------------
__global__ __launch_bounds__(512) void oproj_kernel(
    const _Float16* __restrict__ hohm, const _Float16* __restrict__ Bt,
    const float* __restrict__ bias, float* __restrict__ out)
{
  __shared__ __align__(16) _Float16 Bs[2][320 * 64];   // 80 KB
  const int t = threadIdx.x, lane = t & 63, wave = t >> 6;
  const int m0 = blockIdx.x * 128;
  const int l15 = lane & 15, l4 = lane >> 4;
  const int wbase = t & ~63;
  const int rg = wave >> 1, cg = wave & 1;

  const int gi0 = m0 + rg * 16 + l15;          // subtile 0
  const int gi1 = gi0 + 64;                    // subtile 1
  const int bb0 = gi0 >> 12, ii0 = gi0 & 4095;
  const int bb1 = gi1 >> 12, ii1 = gi1 & 4095;

  vf4 acc[2][10];
#pragma unroll
  for (int s = 0; s < 2; ++s)
#pragma unroll
    for (int bq = 0; bq < 10; ++bq) acc[s][bq] = f4zero();

  vh8 hA[4], hB[4];   // [s*2 + ks]

  // ---- prologue: group(0), group(1) ----
#pragma unroll
  for (int p = 0; p < 5; ++p) {
    int idx = t + p * 512;
    int n = idx >> 3, c8 = idx & 7;
    glds16(Bt + (size_t)n * 320 + 0 + ((c8 ^ (n & 7)) << 3),
           (char*)Bs[0] + (size_t)(p * 512 + wbase) * 16);
  }
#pragma unroll
  for (int ks = 0; ks < 2; ++ks) {
    int k = ks * 32 + l4 * 8;
    int hh = k / 40, d = k - hh * 40;
    hA[0 + ks] = *(const vh8*)(hohm + ((size_t)(bb0 * 8 + hh) * 4096 + ii0) * 40 + d);
    hA[2 + ks] = *(const vh8*)(hohm + ((size_t)(bb1 * 8 + hh) * 4096 + ii1) * 40 + d);
  }
  __builtin_amdgcn_sched_barrier(0);
#pragma unroll
  for (int p = 0; p < 5; ++p) {
    int idx = t + p * 512;
    int n = idx >> 3, c8 = idx & 7;
    glds16(Bt + (size_t)n * 320 + 64 + ((c8 ^ (n & 7)) << 3),
           (char*)Bs[1] + (size_t)(p * 512 + wbase) * 16);
  }
#pragma unroll
  for (int ks = 0; ks < 2; ++ks) {
    int k = 64 + ks * 32 + l4 * 8;
    int hh = k / 40, d = k - hh * 40;
    hB[0 + ks] = *(const vh8*)(hohm + ((size_t)(bb0 * 8 + hh) * 4096 + ii0) * 40 + d);
    hB[2 + ks] = *(const vh8*)(hohm + ((size_t)(bb1 * 8 + hh) * 4096 + ii1) * 40 + d);
  }
  WAITCNT9();
  SBAR();

#pragma unroll
  for (int kc = 0; kc < 5; ++kc) {
    char* BsCur = (char*)Bs[kc & 1];
    vh8* cur = (kc & 1) ? hB : hA;
#pragma unroll
    for (int s = 0; s < 2; ++s) {
#pragma unroll
      for (int ks = 0; ks < 2; ++ks) {
#pragma unroll
        for (int nt = 0; nt < 10; ++nt) {
          int n = cg * 160 + nt * 16 + l15;
          unsigned byte = (unsigned)(n * 128 + (ks * 32 + l4 * 8) * 2) ^ swzB(n);
          vh8 bv = *(const vh8*)(BsCur + byte);
          acc[s][nt] = __builtin_amdgcn_mfma_f32_16x16x32_f16(cur[s * 2 + ks], bv, acc[s][nt], 0, 0, 0);
        }
      }
    }
    if (kc < 4) {
      SBAR();
      if (kc < 3) {
        int k0n = (kc + 2) * 64;
#pragma unroll
        for (int p = 0; p < 5; ++p) {
          int idx = t + p * 512;
          int n = idx >> 3, c8 = idx & 7;
          glds16(Bt + (size_t)n * 320 + k0n + ((c8 ^ (n & 7)) << 3),
                 BsCur + (size_t)(p * 512 + wbase) * 16);
        }
#pragma unroll
        for (int ks = 0; ks < 2; ++ks) {
          int k = k0n + ks * 32 + l4 * 8;
          int hh = k / 40, d = k - hh * 40;
          cur[0 + ks] = *(const vh8*)(hohm + ((size_t)(bb0 * 8 + hh) * 4096 + ii0) * 40 + d);
          cur[2 + ks] = *(const vh8*)(hohm + ((size_t)(bb1 * 8 + hh) * 4096 + ii1) * 40 + d);
        }
        WAITCNT9();
      } else {
        WAITCNT0();
      }
      SBAR();
    }
  }
#pragma unroll
  for (int s = 0; s < 2; ++s)
#pragma unroll
    for (int nt = 0; nt < 10; ++nt) {
      int n = cg * 160 + nt * 16 + l15;
      float bias_v = bias[n];
#pragma unroll
      for (int r = 0; r < 4; ++r) {
        int m = m0 + s * 64 + rg * 16 + l4 * 4 + r;
        out[(size_t)m * 320 + n] = acc[s][nt][r] + bias_v;
      }
    }
}

__global__ __launch_bounds__(256) void finalize_kernel(
    const double* __restrict__ partials, const int* __restrict__ ctypes,
    float* __restrict__ ssb)
{
  __shared__ double rs[256];
  __shared__ double rs2[256];
  __shared__ int rc[256];
  const int t = threadIdx.x;
  double S = 0.0, S2 = 0.0;
#pragma unroll
  for (int p = 0; p < 16; ++p) {
    int idx = t + p * 256;
    S += partials[2 * idx + 0];
    S2 += partials[2 * idx + 1];
  }
  int c = 0;
#pragma unroll
  for (int p = 0; p < 5; ++p) {
    int idx = t + p * 256;
    if (idx < 1232) c += (ctypes[idx] >= 2) ? 1 : 0;
  }
  rs[t] = S; rs2[t] = S2; rc[t] = c;
  __syncthreads();
  for (int off = 128; off > 0; off >>= 1) {
    if (t < off) { rs[t] += rs[t + off]; rs2[t] += rs2[t + off]; rc[t] += rc[t + off]; }
    __syncthreads();
  }
  if (t == 0) {
    double n = (double)rc[0] * 8.0 * 4096.0;
    double mean = rs[0] / n;
    double var = (rs2[0] - n * mean * mean) / (n - 1.0);
    ssb[0] = (float)sqrt(var > 0.0 ? var : 0.0);
  }
}

// ---------------------------------------------------------------------------
// lmask precompute: packed bits lmp[row][qd], qd=j&3, bit m=j>>2.
// ---------------------------------------------------------------------------
__global__ __launch_bounds__(256) void lmask_kernel(
    const float* __restrict__ cam, const int* __restrict__ ctypes,
    const float* __restrict__ ssb, const float* __restrict__ strengthp,
    unsigned* __restrict__ lmp)
{
  __shared__ float camt[64 * 81];
  __shared__ unsigned char gmv[96];
  __shared__ unsigned char m2v[96];
  const int t = threadIdx.x;
  const int it = blockIdx.x, b = blockIdx.y;
  const int i0 = it * 64;

  if (t < 96) {
    int j = t;
    int ct = (j < 77) ? ctypes[b * 77 + j] : -1;
    gmv[j] = (j < 77 && ct >= 0 && ct < 2) ? 1 : 0;
    m2v[j] = (j < 77 && ct >= 2) ? 1 : 0;
  }
#pragma unroll
  for (int p = 0; p < 20; ++p) {
    int idx = t + p * 256;
    int row = idx / 80;
    int j = idx - row * 80;
    camt[row * 81 + j] = (j < 77) ? cam[((size_t)b * 4096 + i0 + row) * 77 + j] : 0.f;
  }
  __syncthreads();

  const float ss = ssb[0];
  const float st = strengthp[0];
  int row = t >> 2, qd = t & 3;
  float wfv[20];
  float wmax = 0.f, wsum = 0.f;
#pragma unroll
  for (int m = 0; m < 20; ++m) {
    int j = qd + 4 * m;
    float wf = 0.f;
    if (j < 77 && m2v[j]) wf = (camt[row * 81 + j] * ss) * st;   // ref assoc order
    wfv[m] = wf;
    wmax = fmaxf(wmax, wf);
    wsum += wf;
  }
  wmax = fmaxf(wmax, __shfl_xor(wmax, 1));
  wmax = fmaxf(wmax, __shfl_xor(wmax, 2));
  wsum += __shfl_xor(wsum, 1);
  wsum += __shfl_xor(wsum, 2);
  float thr = fmaxf(wmax, 0.001f) - 0.0001f;
  bool ug = (wsum == 0.f);
  unsigned wbits = 0u;
#pragma unroll
  for (int m = 0; m < 20; ++m) {
    int j = qd + 4 * m;
    bool lv = (wfv[m] >= thr) || (ug && (j < 77) && gmv[j]);
    if (lv) wbits |= (1u << m);
  }
  lmp[((size_t)b * 4096 + i0 + row) * 4 + qd] = wbits;
}

// ---------------------------------------------------------------------------
// Fused attention: grid (64,16,8), 256 thr. Native __expf softmax.
// ---------------------------------------------------------------------------
__global__ __launch_bounds__(256) void attn_kernel(
    const _Float16* __restrict__ qhm, const _Float16* __restrict__ kf,
    const unsigned* __restrict__ vTg32, const int* __restrict__ ctypes,
    const float* __restrict__ pcb, const unsigned* __restrict__ lmp,
    _Float16* __restrict__ hohm)
{
  __shared__ _Float16 vT[48 * 128];        // [d][j] pitch 256B, XOR swzA(d)
  __shared__ _Float16 attnbuf[64 * 128];   // [row][j] pitch 256B, XOR swzA(row)
  __shared__ __align__(16) _Float16 qt[64 * 40];  // 5120B, reused for PV out
  __shared__ unsigned lmw[256];
  __shared__ float gbf[96];
  __shared__ float nbf[96];

  const int t = threadIdx.x, lane = t & 63, wave = t >> 6;
  const int it = blockIdx.x, b = blockIdx.y, h = blockIdx.z;
  const int i0 = it * 64;
  const int l15 = lane & 15, l4 = lane >> 4;

  if (t < 96) {
    int j = t;
    bool valid = (j < 77);
    int ct = valid ? ctypes[b * 77 + j] : -1;
    bool gm = valid && ct >= 0 && ct < 2;
    gbf[j] = gm ? 0.f : (valid ? NEGBIG : -INFF);
    nbf[j] = valid ? NEGBIG : -INFF;
  }
  lmw[t] = lmp[((size_t)b * 4096 + i0) * 4 + t];

  const _Float16* qsrc = qhm + ((size_t)(b * 8 + h) * 4096 + i0) * 40;
  glds16(qsrc + t * 8, (char*)qt + t * 16);
  if (t < 64) glds16(qsrc + (256 + t) * 8, (char*)qt + (256 + t) * 16);

  {
    const unsigned* src0 = vTg32 + (size_t)(b * 8 + h) * 3072;
#pragma unroll
    for (int p = 0; p < 3; ++p) {
      int idx = t + p * 256;
      glds16(src0 + idx * 4, (char*)vT + (size_t)(p * 256 + (t & ~63)) * 16);
    }
  }
#pragma unroll
  for (int p = 0; p < 2; ++p) {
    int idx = t + p * 256;
    int row = idx >> 3, c = idx & 7;
    unsigned byte = (unsigned)(row * 256 + 160 + c * 4) ^ swzA(row);
    *(unsigned*)((char*)attnbuf + byte) = 0u;
  }

  vh8 k0v[5], k1v[5];
#pragma unroll
  for (int jt = 0; jt < 5; ++jt) {
    int j = jt * 16 + l15;
    k0v[jt] = h8zero(); k1v[jt] = h8zero();
    if (j < 77) {
      const _Float16* kp = kf + (size_t)(b * 77 + j) * 640 + h * 40;
      k0v[jt] = *(const vh8*)(kp + l4 * 8);
      if (l4 == 0) k1v[jt] = *(const vh8*)(kp + 32);
    }
  }

  __syncthreads();

  const int myrow = wave * 16 + l15;
  vh8 qf0 = *(const vh8*)((const char*)qt + myrow * 80 + l4 * 16);
  vh8 qf1 = h8zero();
  if (l4 == 0) qf1 = *(const vh8*)((const char*)qt + myrow * 80 + 64);

  vf4 sacc[5];
#pragma unroll
  for (int jt = 0; jt < 5; ++jt) sacc[jt] = f4zero();
#pragma unroll
  for (int jt = 0; jt < 5; ++jt) {
    sacc[jt] = __builtin_amdgcn_mfma_f32_16x16x32_f16(k0v[jt], qf0, sacc[jt], 0, 0, 0);
    sacc[jt] = __builtin_amdgcn_mfma_f32_16x16x32_f16(k1v[jt], qf1, sacc[jt], 0, 0, 0);
  }

  const float pc0 = pcb[(b * 8 + h) * 2 + 0];
  const float pc1 = pcb[(b * 8 + h) * 2 + 1];
  unsigned wbits[4];
#pragma unroll
  for (int r = 0; r < 4; ++r) wbits[r] = lmw[myrow * 4 + r];

  float gv[5][4], lv[5][4];
  float mg = -INFF, ml = -INFF;
#pragma unroll
  for (int jt = 0; jt < 5; ++jt) {
    int jbase = jt * 16 + l4 * 4;
    float4 gb4 = *(const float4*)&gbf[jbase];
    float4 nb4 = *(const float4*)&nbf[jbase];
    const float* gbp = (const float*)&gb4;
    const float* nbp = (const float*)&nb4;
#pragma unroll
    for (int r = 0; r < 4; ++r) {
      float sv = sacc[jt][r];
      float g = fmaf(sv, SCALE_F, gbp[r]);
      unsigned bit = (wbits[r] >> (jt * 4 + l4)) & 1u;
      float l = fmaf(sv, SCALE_F, bit ? 0.f : nbp[r]);
      gv[jt][r] = g; lv[jt][r] = l;
      mg = fmaxf(mg, g); ml = fmaxf(ml, l);
    }
  }
  mg = fmaxf(mg, __shfl_xor(mg, 16)); mg = fmaxf(mg, __shfl_xor(mg, 32));
  ml = fmaxf(ml, __shfl_xor(ml, 16)); ml = fmaxf(ml, __shfl_xor(ml, 32));
  float sG = 0.f, sL = 0.f;
#pragma unroll
  for (int jt = 0; jt < 5; ++jt)
#pragma unroll
    for (int r = 0; r < 4; ++r) {
      float eg = __expf(gv[jt][r] - mg);
      float el = __expf(lv[jt][r] - ml);
      gv[jt][r] = eg; lv[jt][r] = el;
      sG += eg; sL += el;
    }
  sG += __shfl_xor(sG, 16); sG += __shfl_xor(sG, 32);
  sL += __shfl_xor(sL, 16); sL += __shfl_xor(sL, 32);
  float rG = pc0 / sG, rL = pc1 / sL;
  {
    unsigned swz = swzA(myrow);
    unsigned rowbase = (unsigned)(myrow * 256);
#pragma unroll
    for (int jt = 0; jt < 5; ++jt) {
      vh4 w;
#pragma unroll
      for (int r = 0; r < 4; ++r)
        w[r] = (_Float16)fmaf(gv[jt][r], rG, lv[jt][r] * rL);
      unsigned byte = (rowbase + (unsigned)((jt * 16 + l4 * 4) * 2)) ^ swz;
      *(vh4*)((char*)attnbuf + byte) = w;
    }
  }
  __syncthreads();

  vf4 oacc[3];
#pragma unroll
  for (int nt = 0; nt < 3; ++nt) oacc[nt] = f4zero();
#pragma unroll
  for (int ks = 0; ks < 3; ++ks) {
    int arow = wave * 16 + l15;
    unsigned abyte = (unsigned)(arow * 256 + (ks * 32 + l4 * 8) * 2) ^ swzA(arow);
    vh8 pa = *(const vh8*)((const char*)attnbuf + abyte);
#pragma unroll
    for (int nt = 0; nt < 3; ++nt) {
      int n = nt * 16 + l15;
      unsigned byte = (unsigned)(n * 256 + (ks * 32 + l4 * 8) * 2) ^ swzA(n);
      vh8 vb = *(const vh8*)((const char*)vT + byte);
      oacc[nt] = __builtin_amdgcn_mfma_f32_16x16x32_f16(pa, vb, oacc[nt], 0, 0, 0);
    }
  }
#pragma unroll
  for (int nt = 0; nt < 3; ++nt) {
    int d = nt * 16 + l15;
    if (d < 40) {
#pragma unroll
      for (int r = 0; r < 4; ++r) {
        int m = wave * 16 + l4 * 4 + r;
        qt[m * 40 + d] = (_Float16)oacc[nt][r];
      }
    }
  }
  __syncthreads();

  _Float16* obase = hohm + ((size_t)(b * 8 + h) * 4096 + i0) * 40;
  {
    vh8 v = *(const vh8*)((const char*)qt + t * 16);
    *(vh8*)(obase + t * 8) = v;
  }
  if (t < 64) {
    vh8 v = *(const vh8*)((const char*)qt + (256 + t) * 16);
    *(vh8*)(obase + (256 + t) * 8) = v;
  }
}

// ---------------------------------------------------------------------------
extern "C" void kernel_launch(void* const* d_in, const int* in_sizes, int n_in,
                              void* d_out, int out_size, void* d_ws, size_t ws_size,
                              hipStream_t stream)
{
  const float* x        = (const float*)d_in[0];
  const float* embs     = (const float*)d_in[1];
  const float* cam      = (const float*)d_in[2];
  const float* progress = (const float*)d_in[3];
  const float* strength = (const float*)d_in[4];
  const float* Wq       = (const float*)d_in[5];
  const float* Wk       = (const float*)d_in[6];
  const float* Wv       = (const float*)d_in[7];
  const float* Wo       = (const float*)d_in[8];
  const float* bo       = (const float*)d_in[9];
  const float* emb1     = (const float*)d_in[10];
  const float* emb2     = (const float*)d_in[11];
  const float* Wc1      = (const float*)d_in[12];
  const float* bc1      = (const float*)d_in[13];
  const float* Wc2      = (const float*)d_in[14];
  const float* bc2      = (const float*)d_in[15];
  const int*   ctypes   = (const int*)d_in[16];

  char* w = (char*)d_ws;
  auto alloc = [&](size_t bytes) { char* p = w; w += (bytes + 255) & ~(size_t)255; return p; };
  _Float16* qhm   = (_Float16*)alloc(65536ull * 320 * 2);   // 40 MiB head-major
  _Float16* hohm  = (_Float16*)alloc(65536ull * 320 * 2);   // 40 MiB head-major
  _Float16* kvb   = (_Float16*)alloc(1232ull * 640 * 2);    // 1.5 MiB
  unsigned* vTg   = (unsigned*)alloc(128ull * 3072 * 4);    // 1.5 MiB
  _Float16* WqT   = (_Float16*)alloc(320ull * 320 * 2);
  _Float16* WkvT  = (_Float16*)alloc(640ull * 768 * 2);
  _Float16* WoT   = (_Float16*)alloc(320ull * 320 * 2);
  unsigned* lmp   = (unsigned*)alloc(65536ull * 4 * 4);     // 1 MiB
  float*    pcb   = (float*)alloc(256 * 4);
  double*   part  = (double*)alloc(4096ull * 2 * 8);        // 64 KiB
  float*    ssb   = (float*)alloc(256);

  prep_kernel<<<696, 256, 0, stream>>>(Wq, Wk, Wv, Wo, WqT, WkvT, WoT,
                                       progress, emb1, emb2, Wc1, bc1, Wc2, bc2, pcb);
  kv_gemm_kernel<<<dim3(20, 4), 256, 0, stream>>>(embs, WkvT, kvb);
  qproj_kernel<<<640, 512, 0, stream>>>(x, WqT, kvb, ctypes, qhm, part, kvb + 320, vTg);
  finalize_kernel<<<1, 256, 0, stream>>>(part, ctypes, ssb);
  lmask_kernel<<<dim3(64, 16), 256, 0, stream>>>(cam, ctypes, ssb, strength, lmp);
  attn_kernel<<<dim3(64, 16, 8), 256, 0, stream>>>(qhm, kvb, vTg, ctypes, pcb, lmp, hohm);
  oproj_kernel<<<512, 512, 0, stream>>>(hohm, WoT, bo, (float*)d_out);
}

// Round 19
// 242.213 us; speedup vs baseline: 1.0396x; 1.0046x over previous
//
#include <hip/hip_runtime.h>

// ---------------------------------------------------------------------------
// CustomCrossAttentionMinimal on MI355X (gfx950)
// b=16, i=4096, j=77, qd=320, cd=768, H=8, DH=40, inner=320
// Layouts: qhm/hohm are head-major fp16 [b][h][4096][40]
// ---------------------------------------------------------------------------

typedef _Float16 vh8 __attribute__((ext_vector_type(8)));
typedef _Float16 vh4 __attribute__((ext_vector_type(4)));
typedef float    vf4 __attribute__((ext_vector_type(4)));

#define NEGBIG  (-3.4028235e38f)
#define SCALE_F 0.15811388300841897f     // 40^-0.5
#define INFF    (__builtin_inff())

#define WAITCNT9() do { asm volatile("s_waitcnt vmcnt(9)" ::: "memory"); __builtin_amdgcn_sched_barrier(0); } while (0)
#define WAITCNT0() do { asm volatile("s_waitcnt vmcnt(0)" ::: "memory"); __builtin_amdgcn_sched_barrier(0); } while (0)
#define SBAR()     __builtin_amdgcn_s_barrier()

__device__ __forceinline__ vh8 h8zero() {
  vh8 v;
#pragma unroll
  for (int i = 0; i < 8; ++i) v[i] = (_Float16)0.f;
  return v;
}
__device__ __forceinline__ vf4 f4zero() {
  vf4 v;
#pragma unroll
  for (int i = 0; i < 4; ++i) v[i] = 0.f;
  return v;
}
__device__ __forceinline__ float gelu_exact(float x) {
  return 0.5f * x * (1.0f + erff(x * 0.70710678118654752f));
}
__device__ __forceinline__ unsigned swzA(int row) {
  return (unsigned)(((row & 7) << 4) ^ (((row >> 3) & 1) << 5));
}
__device__ __forceinline__ unsigned swzB(int row) {
  return (unsigned)((row & 7) << 4);
}
__device__ __forceinline__ void glds16(const void* g, void* l) {
  __builtin_amdgcn_global_load_lds((const __attribute__((address_space(1))) unsigned*)g,
                                   (__attribute__((address_space(3))) unsigned*)l, 16, 0, 0);
}

// ---------------------------------------------------------------------------
// prep kernel: blocks 0..679 = tiled weight transpose (fp32 -> fp16 [N][K]);
// blocks 680..695 = progress classifier (b = blockIdx - 680). 256 thr.
// ---------------------------------------------------------------------------
__global__ __launch_bounds__(256) void prep_kernel(
    const float* __restrict__ Wq, const float* __restrict__ Wk,
    const float* __restrict__ Wv, const float* __restrict__ Wo,
    _Float16* __restrict__ WqT, _Float16* __restrict__ WkvT, _Float16* __restrict__ WoT,
    const float* __restrict__ progress,
    const float* __restrict__ emb1, const float* __restrict__ emb2,
    const float* __restrict__ Wc1, const float* __restrict__ bc1,
    const float* __restrict__ Wc2, const float* __restrict__ bc2,
    float* __restrict__ pcb)
{
  if (blockIdx.x < 680) {
    __shared__ float ts[32][33];
    int tile = blockIdx.x;
    const float* src; _Float16* dst; int dstK, rowOff;
    if (tile < 100)      { src = Wq; dst = WqT;  dstK = 320; rowOff = 0; }
    else if (tile < 340) { src = Wk; dst = WkvT; dstK = 768; rowOff = 0;   tile -= 100; }
    else if (tile < 580) { src = Wv; dst = WkvT; dstK = 768; rowOff = 320; tile -= 340; }
    else                 { src = Wo; dst = WoT;  dstK = 320; rowOff = 0;   tile -= 580; }
    int kb = tile / 10, nb = tile - kb * 10;
    int k0 = kb * 32, n0 = nb * 32;
    int r = threadIdx.x >> 5, c = threadIdx.x & 31;
#pragma unroll
    for (int p = 0; p < 4; ++p)
      ts[r + p * 8][c] = src[(size_t)(k0 + r + p * 8) * 320 + n0 + c];
    __syncthreads();
#pragma unroll
    for (int p = 0; p < 4; ++p)
      dst[(size_t)(rowOff + n0 + r + p * 8) * dstK + k0 + c] = (_Float16)ts[c][r + p * 8];
    return;
  }
  // classifier path
  {
    __shared__ float g[512];
    __shared__ float h1[512];
    __shared__ float lg[16];
    const int b = blockIdx.x - 680;
    const int t = threadIdx.x;

    float pr = progress[b];
    int xstep = (int)rintf(pr * 1000.0f);
    if (xstep > 999) xstep = 999;
    int a = xstep / 20;
    int r = xstep - a * 20;

    for (int d = t; d < 512; d += 256) {
      float e = emb1[a * 512 + d] + emb2[r * 512 + d];
      g[d] = gelu_exact(e);
    }
    __syncthreads();
    for (int n = t; n < 512; n += 256) {
      float acc = bc1[n];
      for (int d = 0; d < 512; ++d) acc = fmaf(g[d], Wc1[d * 512 + n], acc);
      h1[n] = gelu_exact(acc);
    }
    __syncthreads();
    if (t < 16) {
      float acc = bc2[t];
      for (int d = 0; d < 512; ++d) acc = fmaf(h1[d], Wc2[d * 16 + t], acc);
      lg[t] = acc;
    }
    __syncthreads();
    if (t < 8) {
      float a0 = lg[2 * t], a1 = lg[2 * t + 1];
      float mx = fmaxf(a0, a1);
      float e0 = __expf(a0 - mx), e1 = __expf(a1 - mx);
      float inv = 1.0f / (e0 + e1);
      pcb[(b * 8 + t) * 2 + 0] = e0 * inv;
      pcb[(b * 8 + t) * 2 + 1] = e1 * inv;
    }
  }
}

// ---------------------------------------------------------------------------
// KV GEMM (barrier-free): C[1232,640] = embs[1232,768] @ WkvT[640,768]^T
// ---------------------------------------------------------------------------
__global__ __launch_bounds__(256) void kv_gemm_kernel(
    const float* __restrict__ Ap, const _Float16* __restrict__ Bt,
    _Float16* __restrict__ Cp)
{
  const int t = threadIdx.x, lane = t & 63, wave = t >> 6;
  const int m0 = blockIdx.x * 64;
  const int n0 = blockIdx.y * 160;
  const int l15 = lane & 15, l4 = lane >> 4;
  const int rg = wave >> 1, cg = wave & 1;

  vf4 acc[2][5];
#pragma unroll
  for (int a = 0; a < 2; ++a)
#pragma unroll
    for (int bq = 0; bq < 5; ++bq) acc[a][bq] = f4zero();

#pragma unroll 2
  for (int kk = 0; kk < 24; ++kk) {
    int k = kk * 32 + l4 * 8;
    vh8 av[2];
#pragma unroll
    for (int mt = 0; mt < 2; ++mt) {
      int row = m0 + rg * 32 + mt * 16 + l15;
      av[mt] = h8zero();
      if (row < 1232) {
        const float* ap = Ap + (size_t)row * 768 + k;
        float4 f0 = *(const float4*)ap;
        float4 f1 = *(const float4*)(ap + 4);
        vh8 hv;
        hv[0] = (_Float16)f0.x; hv[1] = (_Float16)f0.y; hv[2] = (_Float16)f0.z; hv[3] = (_Float16)f0.w;
        hv[4] = (_Float16)f1.x; hv[5] = (_Float16)f1.y; hv[6] = (_Float16)f1.z; hv[7] = (_Float16)f1.w;
        av[mt] = hv;
      }
    }
#pragma unroll
    for (int nt = 0; nt < 5; ++nt) {
      int n = n0 + cg * 80 + nt * 16 + l15;
      vh8 bv = *(const vh8*)(Bt + (size_t)n * 768 + k);
      acc[0][nt] = __builtin_amdgcn_mfma_f32_16x16x32_f16(av[0], bv, acc[0][nt], 0, 0, 0);
      acc[1][nt] = __builtin_amdgcn_mfma_f32_16x16x32_f16(av[1], bv, acc[1][nt], 0, 0, 0);
    }
  }
#pragma unroll
  for (int mt = 0; mt < 2; ++mt)
#pragma unroll
    for (int nt = 0; nt < 5; ++nt) {
      int n = n0 + cg * 80 + nt * 16 + l15;
#pragma unroll
      for (int r = 0; r < 4; ++r) {
        int m = m0 + rg * 32 + mt * 16 + l4 * 4 + r;
        if (m < 1232) Cp[(size_t)m * 640 + n] = (_Float16)acc[mt][nt][r];
      }
    }
}

// ---------------------------------------------------------------------------
// Q projection + fused std + (blocks >=512) V^T pre-swizzle.
// 512 thr, 8 waves, BM=128 (2 subtiles of 64 rows). Counted-vmcnt 2-deep.
// ---------------------------------------------------------------------------
__global__ __launch_bounds__(512) void qproj_kernel(
    const float* __restrict__ x, const _Float16* __restrict__ Bt,
    const _Float16* __restrict__ kf, const int* __restrict__ ctypes,
    _Float16* __restrict__ qhm, double* __restrict__ partials,
    const _Float16* __restrict__ vf, unsigned* __restrict__ vTg32)
{
  __shared__ __align__(16) char smem[81920];   // buf0 @0, buf1 @40960; buf0 reused for re-tile
  const int t = threadIdx.x, lane = t & 63, wave = t >> 6;

  if (blockIdx.x >= 512) {
    // vtrans path: vb in 0..127 -> (b, h)
    int vb = blockIdx.x - 512;
    int b = vb >> 3, h = vb & 7;
    unsigned* out = vTg32 + (size_t)(b * 8 + h) * 3072;
#pragma unroll
    for (int p = 0; p < 6; ++p) {
      int idx = t + p * 512;            // u32 index 0..3071
      int d = idx >> 6;
      int u = idx & 63;
      int c = u >> 2, pr = u & 3;
      int sd = (int)(swzA(d) >> 4);
      int j0 = ((c ^ sd) << 3) + pr * 2;
      unsigned lo = 0, hi = 0;
      if (d < 40) {
        if (j0 < 77)     lo = *(const unsigned short*)(vf + (size_t)(b * 77 + j0) * 640 + h * 40 + d);
        if (j0 + 1 < 77) hi = *(const unsigned short*)(vf + (size_t)(b * 77 + j0 + 1) * 640 + h * 40 + d);
      }
      out[idx] = lo | (hi << 16);
    }
    return;
  }

  const int m0 = blockIdx.x * 128;
  const int l15 = lane & 15, l4 = lane >> 4;
  const int wbase = t & ~63;
  const int rg = wave >> 1, cg = wave & 1;          // rg 0..3, cg 0..1
  const float* arow0 = x + (size_t)(m0 + rg * 16 + l15) * 320 + l4 * 8;        // subtile 0
  const float* arow1 = x + (size_t)(m0 + 64 + rg * 16 + l15) * 320 + l4 * 8;   // subtile 1

  vf4 acc[2][10];
#pragma unroll
  for (int s = 0; s < 2; ++s)
#pragma unroll
    for (int bq = 0; bq < 10; ++bq) acc[s][bq] = f4zero();

  float4 fA[8], fB[8];   // [s*4 + ks*2 + half]

  // ---- prologue: group(0) = B(0)+A(0); group(1) = B(1)+A(1) ----
#pragma unroll
  for (int p = 0; p < 5; ++p) {
    int idx = t + p * 512;
    int n = idx >> 3, c8 = idx & 7;
    glds16(Bt + (size_t)n * 320 + 0 + ((c8 ^ (n & 7)) << 3),
           smem + (size_t)(p * 512 + wbase) * 16);
  }
#pragma unroll
  for (int ks = 0; ks < 2; ++ks) {
    fA[0 + ks * 2 + 0] = *(const float4*)(arow0 + ks * 32);
    fA[0 + ks * 2 + 1] = *(const float4*)(arow0 + ks * 32 + 4);
    fA[4 + ks * 2 + 0] = *(const float4*)(arow1 + ks * 32);
    fA[4 + ks * 2 + 1] = *(const float4*)(arow1 + ks * 32 + 4);
  }
  __builtin_amdgcn_sched_barrier(0);   // group(0) fully issued before group(1)
#pragma unroll
  for (int p = 0; p < 5; ++p) {
    int idx = t + p * 512;
    int n = idx >> 3, c8 = idx & 7;
    glds16(Bt + (size_t)n * 320 + 64 + ((c8 ^ (n & 7)) << 3),
           smem + 40960 + (size_t)(p * 512 + wbase) * 16);
  }
#pragma unroll
  for (int ks = 0; ks < 2; ++ks) {
    fB[0 + ks * 2 + 0] = *(const float4*)(arow0 + 64 + ks * 32);
    fB[0 + ks * 2 + 1] = *(const float4*)(arow0 + 64 + ks * 32 + 4);
    fB[4 + ks * 2 + 0] = *(const float4*)(arow1 + 64 + ks * 32);
    fB[4 + ks * 2 + 1] = *(const float4*)(arow1 + 64 + ks * 32 + 4);
  }
  WAITCNT9();        // group(0) complete; group(1) may remain in flight
  SBAR();

#pragma unroll
  for (int kc = 0; kc < 5; ++kc) {
    char* BsCur = smem + (size_t)(kc & 1) * 40960;
    float4* cur = (kc & 1) ? fB : fA;
    // compute tile kc
#pragma unroll
    for (int s = 0; s < 2; ++s) {
#pragma unroll
      for (int ks = 0; ks < 2; ++ks) {
        float4 f0 = cur[s * 4 + ks * 2 + 0];
        float4 f1 = cur[s * 4 + ks * 2 + 1];
        vh8 av;
        av[0] = (_Float16)f0.x; av[1] = (_Float16)f0.y; av[2] = (_Float16)f0.z; av[3] = (_Float16)f0.w;
        av[4] = (_Float16)f1.x; av[5] = (_Float16)f1.y; av[6] = (_Float16)f1.z; av[7] = (_Float16)f1.w;
#pragma unroll
        for (int nt = 0; nt < 10; ++nt) {
          int n = cg * 160 + nt * 16 + l15;
          unsigned byte = (unsigned)(n * 128 + (ks * 32 + l4 * 8) * 2) ^ swzB(n);
          vh8 bv = *(const vh8*)(BsCur + byte);
          acc[s][nt] = __builtin_amdgcn_mfma_f32_16x16x32_f16(av, bv, acc[s][nt], 0, 0, 0);
        }
      }
    }
    if (kc < 4) {
      SBAR();                      // all waves done reading buf[kc&1]
      if (kc < 3) {
        int k0n = (kc + 2) * 64;   // stage group(kc+2) into buf[kc&1]
#pragma unroll
        for (int p = 0; p < 5; ++p) {
          int idx = t + p * 512;
          int n = idx >> 3, c8 = idx & 7;
          glds16(Bt + (size_t)n * 320 + k0n + ((c8 ^ (n & 7)) << 3),
                 BsCur + (size_t)(p * 512 + wbase) * 16);
        }
#pragma unroll
        for (int ks = 0; ks < 2; ++ks) {
          cur[0 + ks * 2 + 0] = *(const float4*)(arow0 + k0n + ks * 32);
          cur[0 + ks * 2 + 1] = *(const float4*)(arow0 + k0n + ks * 32 + 4);
          cur[4 + ks * 2 + 0] = *(const float4*)(arow1 + k0n + ks * 32);
          cur[4 + ks * 2 + 1] = *(const float4*)(arow1 + k0n + ks * 32 + 4);
        }
        WAITCNT9();                // group(kc+1) complete
      } else {
        WAITCNT0();                // kc==3: group(4) complete
      }
      SBAR();                      // buf[(kc+1)&1] visible to all waves
    }
  }
  __syncthreads();                 // protect buf0 before epilogue reuse

  // per-subtile epilogue: re-tile -> scatter -> fused std
  double S = 0.0, S2 = 0.0;
  const int b = m0 >> 12;
  const int h = wave;
#pragma unroll
  for (int s = 0; s < 2; ++s) {
#pragma unroll
    for (int nt = 0; nt < 10; ++nt) {
      int col = cg * 160 + nt * 16 + l15;
#pragma unroll
      for (int r = 0; r < 4; ++r) {
        int lr = rg * 16 + l4 * 4 + r;
        unsigned byte = (unsigned)(lr * 640 + col * 2) ^ swzB(lr);
        *(_Float16*)(smem + byte) = (_Float16)acc[s][nt][r];
      }
    }
    __syncthreads();
#pragma unroll
    for (int p = 0; p < 5; ++p) {
      int idx = t + p * 512;               // 0..2559 = 64 rows x 8 heads x 5 chunks
      int hh = idx / 320;
      int rem = idx - hh * 320;
      int lrow = rem / 5;
      int c = rem - lrow * 5;
      unsigned sb = (unsigned)(lrow * 640 + hh * 80 + c * 16) ^ swzB(lrow);
      vh8 v = *(const vh8*)(smem + sb);
      int gi = m0 + s * 64 + lrow;
      int bb = gi >> 12, ii = gi & 4095;
      *(vh8*)(qhm + ((size_t)(bb * 8 + hh) * 4096 + ii) * 40 + c * 8) = v;
    }
    {
      vh8 a0v[4], a1v[4];
#pragma unroll
      for (int mt = 0; mt < 4; ++mt) {
        int qrow = mt * 16 + l15;
        unsigned b0 = (unsigned)(qrow * 640 + (h * 40 + l4 * 8) * 2) ^ swzB(qrow);
        a0v[mt] = *(const vh8*)(smem + b0);
        a1v[mt] = h8zero();
        if (l4 == 0) {
          unsigned b1 = (unsigned)(qrow * 640 + (h * 40 + 32) * 2) ^ swzB(qrow);
          a1v[mt] = *(const vh8*)(smem + b1);
        }
      }
#pragma unroll
      for (int jt = 0; jt < 5; ++jt) {
        int j = jt * 16 + l15;
        bool valid = (j < 77);
        vh8 b0 = h8zero(), b1 = h8zero();
        int ctj = -1;
        if (valid) {
          const _Float16* kp = kf + (size_t)(b * 77 + j) * 640 + h * 40;
          b0 = *(const vh8*)(kp + l4 * 8);
          if (l4 == 0) b1 = *(const vh8*)(kp + 32);
          ctj = ctypes[b * 77 + j];
        }
#pragma unroll
        for (int mt = 0; mt < 4; ++mt) {
          vf4 sv4 = f4zero();
          sv4 = __builtin_amdgcn_mfma_f32_16x16x32_f16(a0v[mt], b0, sv4, 0, 0, 0);
          sv4 = __builtin_amdgcn_mfma_f32_16x16x32_f16(a1v[mt], b1, sv4, 0, 0, 0);
          if (ctj >= 2) {
#pragma unroll
            for (int r = 0; r < 4; ++r) {
              double sv = (double)sv4[r];
              S += sv; S2 += sv * sv;
            }
          }
        }
      }
    }
    __syncthreads();
  }
#pragma unroll
  for (int off = 32; off > 0; off >>= 1) {
    S += __shfl_xor(S, off);
    S2 += __shfl_xor(S2, off);
  }
  if (lane == 0) {
    int idx = blockIdx.x * 8 + wave;
    partials[2 * idx + 0] = S;
    partials[2 * idx + 1] = S2;
  }
}

// ---------------------------------------------------------------------------
// O projection: 512 thr, 8 waves, BM=128 (2 subtiles). Counted-vmcnt 2-deep.
// ---------------------------------------------------------------------------
__global__ __launch_bounds__(512) void oproj_kernel(
    const _Float16* __restrict__ hohm, const _Float16* __restrict__ Bt,
    const float* __restrict__ bias, float* __restrict__ out)
{
  __shared__ __align__(16) _Float16 Bs[2][320 * 64];   // 80 KB
  const int t = threadIdx.x, lane = t & 63, wave = t >> 6;
  const int m0 = blockIdx.x * 128;
  const int l15 = lane & 15, l4 = lane >> 4;
  const int wbase = t & ~63;
  const int rg = wave >> 1, cg = wave & 1;

  const int gi0 = m0 + rg * 16 + l15;          // subtile 0
  const int gi1 = gi0 + 64;                    // subtile 1
  const int bb0 = gi0 >> 12, ii0 = gi0 & 4095;
  const int bb1 = gi1 >> 12, ii1 = gi1 & 4095;

  vf4 acc[2][10];
#pragma unroll
  for (int s = 0; s < 2; ++s)
#pragma unroll
    for (int bq = 0; bq < 10; ++bq) acc[s][bq] = f4zero();

  vh8 hA[4], hB[4];   // [s*2 + ks]

  // ---- prologue: group(0), group(1) ----
#pragma unroll
  for (int p = 0; p < 5; ++p) {
    int idx = t + p * 512;
    int n = idx >> 3, c8 = idx & 7;
    glds16(Bt + (size_t)n * 320 + 0 + ((c8 ^ (n & 7)) << 3),
           (char*)Bs[0] + (size_t)(p * 512 + wbase) * 16);
  }
#pragma unroll
  for (int ks = 0; ks < 2; ++ks) {
    int k = ks * 32 + l4 * 8;
    int hh = k / 40, d = k - hh * 40;
    hA[0 + ks] = *(const vh8*)(hohm + ((size_t)(bb0 * 8 + hh) * 4096 + ii0) * 40 + d);
    hA[2 + ks] = *(const vh8*)(hohm + ((size_t)(bb1 * 8 + hh) * 4096 + ii1) * 40 + d);
  }
  __builtin_amdgcn_sched_barrier(0);
#pragma unroll
  for (int p = 0; p < 5; ++p) {
    int idx = t + p * 512;
    int n = idx >> 3, c8 = idx & 7;
    glds16(Bt + (size_t)n * 320 + 64 + ((c8 ^ (n & 7)) << 3),
           (char*)Bs[1] + (size_t)(p * 512 + wbase) * 16);
  }
#pragma unroll
  for (int ks = 0; ks < 2; ++ks) {
    int k = 64 + ks * 32 + l4 * 8;
    int hh = k / 40, d = k - hh * 40;
    hB[0 + ks] = *(const vh8*)(hohm + ((size_t)(bb0 * 8 + hh) * 4096 + ii0) * 40 + d);
    hB[2 + ks] = *(const vh8*)(hohm + ((size_t)(bb1 * 8 + hh) * 4096 + ii1) * 40 + d);
  }
  WAITCNT9();
  SBAR();

#pragma unroll
  for (int kc = 0; kc < 5; ++kc) {
    char* BsCur = (char*)Bs[kc & 1];
    vh8* cur = (kc & 1) ? hB : hA;
#pragma unroll
    for (int s = 0; s < 2; ++s) {
#pragma unroll
      for (int ks = 0; ks < 2; ++ks) {
#pragma unroll
        for (int nt = 0; nt < 10; ++nt) {
          int n = cg * 160 + nt * 16 + l15;
          unsigned byte = (unsigned)(n * 128 + (ks * 32 + l4 * 8) * 2) ^ swzB(n);
          vh8 bv = *(const vh8*)(BsCur + byte);
          acc[s][nt] = __builtin_amdgcn_mfma_f32_16x16x32_f16(cur[s * 2 + ks], bv, acc[s][nt], 0, 0, 0);
        }
      }
    }
    if (kc < 4) {
      SBAR();
      if (kc < 3) {
        int k0n = (kc + 2) * 64;
#pragma unroll
        for (int p = 0; p < 5; ++p) {
          int idx = t + p * 512;
          int n = idx >> 3, c8 = idx & 7;
          glds16(Bt + (size_t)n * 320 + k0n + ((c8 ^ (n & 7)) << 3),
                 BsCur + (size_t)(p * 512 + wbase) * 16);
        }
#pragma unroll
        for (int ks = 0; ks < 2; ++ks) {
          int k = k0n + ks * 32 + l4 * 8;
          int hh = k / 40, d = k - hh * 40;
          cur[0 + ks] = *(const vh8*)(hohm + ((size_t)(bb0 * 8 + hh) * 4096 + ii0) * 40 + d);
          cur[2 + ks] = *(const vh8*)(hohm + ((size_t)(bb1 * 8 + hh) * 4096 + ii1) * 40 + d);
        }
        WAITCNT9();
      } else {
        WAITCNT0();
      }
      SBAR();
    }
  }
#pragma unroll
  for (int s = 0; s < 2; ++s)
#pragma unroll
    for (int nt = 0; nt < 10; ++nt) {
      int n = cg * 160 + nt * 16 + l15;
      float bias_v = bias[n];
#pragma unroll
      for (int r = 0; r < 4; ++r) {
        int m = m0 + s * 64 + rg * 16 + l4 * 4 + r;
        out[(size_t)m * 320 + n] = acc[s][nt][r] + bias_v;
      }
    }
}

// ---------------------------------------------------------------------------
// lmask + inline finalize: each block reduces partials (4096 pairs) to simstd,
// then computes packed lmask bits. Grid (64,16), 256 thr.
// ---------------------------------------------------------------------------
__global__ __launch_bounds__(256) void lmask_kernel(
    const float* __restrict__ cam, const int* __restrict__ ctypes,
    const double* __restrict__ partials, const float* __restrict__ strengthp,
    unsigned* __restrict__ lmp)
{
  __shared__ float camt[64 * 81];
  __shared__ unsigned char gmv[96];
  __shared__ unsigned char m2v[96];
  __shared__ double rs[256];
  __shared__ double rs2[256];
  __shared__ int rc[256];
  __shared__ float ssv;
  const int t = threadIdx.x;
  const int it = blockIdx.x, b = blockIdx.y;
  const int i0 = it * 64;

  if (t < 96) {
    int j = t;
    int ct = (j < 77) ? ctypes[b * 77 + j] : -1;
    gmv[j] = (j < 77 && ct >= 0 && ct < 2) ? 1 : 0;
    m2v[j] = (j < 77 && ct >= 2) ? 1 : 0;
  }
#pragma unroll
  for (int p = 0; p < 20; ++p) {
    int idx = t + p * 256;
    int row = idx / 80;
    int j = idx - row * 80;
    camt[row * 81 + j] = (j < 77) ? cam[((size_t)b * 4096 + i0 + row) * 77 + j] : 0.f;
  }
  // inline finalize: reduce 4096 partial pairs + ctype count
  {
    double S = 0.0, S2 = 0.0;
#pragma unroll
    for (int p = 0; p < 16; ++p) {
      int idx = t + p * 256;
      S += partials[2 * idx + 0];
      S2 += partials[2 * idx + 1];
    }
    int c = 0;
#pragma unroll
    for (int p = 0; p < 5; ++p) {
      int idx = t + p * 256;
      if (idx < 1232) c += (ctypes[idx] >= 2) ? 1 : 0;
    }
    rs[t] = S; rs2[t] = S2; rc[t] = c;
    __syncthreads();
    for (int off = 128; off > 0; off >>= 1) {
      if (t < off) { rs[t] += rs[t + off]; rs2[t] += rs2[t + off]; rc[t] += rc[t + off]; }
      __syncthreads();
    }
    if (t == 0) {
      double n = (double)rc[0] * 8.0 * 4096.0;
      double mean = rs[0] / n;
      double var = (rs2[0] - n * mean * mean) / (n - 1.0);
      ssv = (float)sqrt(var > 0.0 ? var : 0.0);
    }
  }
  __syncthreads();

  const float ss = ssv;
  const float st = strengthp[0];
  int row = t >> 2, qd = t & 3;
  float wfv[20];
  float wmax = 0.f, wsum = 0.f;
#pragma unroll
  for (int m = 0; m < 20; ++m) {
    int j = qd + 4 * m;
    float wf = 0.f;
    if (j < 77 && m2v[j]) wf = (camt[row * 81 + j] * ss) * st;   // ref assoc order
    wfv[m] = wf;
    wmax = fmaxf(wmax, wf);
    wsum += wf;
  }
  wmax = fmaxf(wmax, __shfl_xor(wmax, 1));
  wmax = fmaxf(wmax, __shfl_xor(wmax, 2));
  wsum += __shfl_xor(wsum, 1);
  wsum += __shfl_xor(wsum, 2);
  float thr = fmaxf(wmax, 0.001f) - 0.0001f;
  bool ug = (wsum == 0.f);
  unsigned wbits = 0u;
#pragma unroll
  for (int m = 0; m < 20; ++m) {
    int j = qd + 4 * m;
    bool lv = (wfv[m] >= thr) || (ug && (j < 77) && gmv[j]);
    if (lv) wbits |= (1u << m);
  }
  lmp[((size_t)b * 4096 + i0 + row) * 4 + qd] = wbits;
}

// ---------------------------------------------------------------------------
// Fused attention: grid (64,16,8), 256 thr. Native __expf softmax.
// ---------------------------------------------------------------------------
__global__ __launch_bounds__(256) void attn_kernel(
    const _Float16* __restrict__ qhm, const _Float16* __restrict__ kf,
    const unsigned* __restrict__ vTg32, const int* __restrict__ ctypes,
    const float* __restrict__ pcb, const unsigned* __restrict__ lmp,
    _Float16* __restrict__ hohm)
{
  __shared__ _Float16 vT[48 * 128];        // [d][j] pitch 256B, XOR swzA(d)
  __shared__ _Float16 attnbuf[64 * 128];   // [row][j] pitch 256B, XOR swzA(row)
  __shared__ __align__(16) _Float16 qt[64 * 40];  // 5120B, reused for PV out
  __shared__ unsigned lmw[256];
  __shared__ float gbf[96];
  __shared__ float nbf[96];

  const int t = threadIdx.x, lane = t & 63, wave = t >> 6;
  const int it = blockIdx.x, b = blockIdx.y, h = blockIdx.z;
  const int i0 = it * 64;
  const int l15 = lane & 15, l4 = lane >> 4;

  if (t < 96) {
    int j = t;
    bool valid = (j < 77);
    int ct = valid ? ctypes[b * 77 + j] : -1;
    bool gm = valid && ct >= 0 && ct < 2;
    gbf[j] = gm ? 0.f : (valid ? NEGBIG : -INFF);
    nbf[j] = valid ? NEGBIG : -INFF;
  }
  lmw[t] = lmp[((size_t)b * 4096 + i0) * 4 + t];

  const _Float16* qsrc = qhm + ((size_t)(b * 8 + h) * 4096 + i0) * 40;
  glds16(qsrc + t * 8, (char*)qt + t * 16);
  if (t < 64) glds16(qsrc + (256 + t) * 8, (char*)qt + (256 + t) * 16);

  {
    const unsigned* src0 = vTg32 + (size_t)(b * 8 + h) * 3072;
#pragma unroll
    for (int p = 0; p < 3; ++p) {
      int idx = t + p * 256;
      glds16(src0 + idx * 4, (char*)vT + (size_t)(p * 256 + (t & ~63)) * 16);
    }
  }
#pragma unroll
  for (int p = 0; p < 2; ++p) {
    int idx = t + p * 256;
    int row = idx >> 3, c = idx & 7;
    unsigned byte = (unsigned)(row * 256 + 160 + c * 4) ^ swzA(row);
    *(unsigned*)((char*)attnbuf + byte) = 0u;
  }

  vh8 k0v[5], k1v[5];
#pragma unroll
  for (int jt = 0; jt < 5; ++jt) {
    int j = jt * 16 + l15;
    k0v[jt] = h8zero(); k1v[jt] = h8zero();
    if (j < 77) {
      const _Float16* kp = kf + (size_t)(b * 77 + j) * 640 + h * 40;
      k0v[jt] = *(const vh8*)(kp + l4 * 8);
      if (l4 == 0) k1v[jt] = *(const vh8*)(kp + 32);
    }
  }

  __syncthreads();

  const int myrow = wave * 16 + l15;
  vh8 qf0 = *(const vh8*)((const char*)qt + myrow * 80 + l4 * 16);
  vh8 qf1 = h8zero();
  if (l4 == 0) qf1 = *(const vh8*)((const char*)qt + myrow * 80 + 64);

  vf4 sacc[5];
#pragma unroll
  for (int jt = 0; jt < 5; ++jt) sacc[jt] = f4zero();
#pragma unroll
  for (int jt = 0; jt < 5; ++jt) {
    sacc[jt] = __builtin_amdgcn_mfma_f32_16x16x32_f16(k0v[jt], qf0, sacc[jt], 0, 0, 0);
    sacc[jt] = __builtin_amdgcn_mfma_f32_16x16x32_f16(k1v[jt], qf1, sacc[jt], 0, 0, 0);
  }

  const float pc0 = pcb[(b * 8 + h) * 2 + 0];
  const float pc1 = pcb[(b * 8 + h) * 2 + 1];
  unsigned wbits[4];
#pragma unroll
  for (int r = 0; r < 4; ++r) wbits[r] = lmw[myrow * 4 + r];

  float gv[5][4], lv[5][4];
  float mg = -INFF, ml = -INFF;
#pragma unroll
  for (int jt = 0; jt < 5; ++jt) {
    int jbase = jt * 16 + l4 * 4;
    float4 gb4 = *(const float4*)&gbf[jbase];
    float4 nb4 = *(const float4*)&nbf[jbase];
    const float* gbp = (const float*)&gb4;
    const float* nbp = (const float*)&nb4;
#pragma unroll
    for (int r = 0; r < 4; ++r) {
      float sv = sacc[jt][r];
      float g = fmaf(sv, SCALE_F, gbp[r]);
      unsigned bit = (wbits[r] >> (jt * 4 + l4)) & 1u;
      float l = fmaf(sv, SCALE_F, bit ? 0.f : nbp[r]);
      gv[jt][r] = g; lv[jt][r] = l;
      mg = fmaxf(mg, g); ml = fmaxf(ml, l);
    }
  }
  mg = fmaxf(mg, __shfl_xor(mg, 16)); mg = fmaxf(mg, __shfl_xor(mg, 32));
  ml = fmaxf(ml, __shfl_xor(ml, 16)); ml = fmaxf(ml, __shfl_xor(ml, 32));
  float sG = 0.f, sL = 0.f;
#pragma unroll
  for (int jt = 0; jt < 5; ++jt)
#pragma unroll
    for (int r = 0; r < 4; ++r) {
      float eg = __expf(gv[jt][r] - mg);
      float el = __expf(lv[jt][r] - ml);
      gv[jt][r] = eg; lv[jt][r] = el;
      sG += eg; sL += el;
    }
  sG += __shfl_xor(sG, 16); sG += __shfl_xor(sG, 32);
  sL += __shfl_xor(sL, 16); sL += __shfl_xor(sL, 32);
  float rG = pc0 / sG, rL = pc1 / sL;
  {
    unsigned swz = swzA(myrow);
    unsigned rowbase = (unsigned)(myrow * 256);
#pragma unroll
    for (int jt = 0; jt < 5; ++jt) {
      vh4 w;
#pragma unroll
      for (int r = 0; r < 4; ++r)
        w[r] = (_Float16)fmaf(gv[jt][r], rG, lv[jt][r] * rL);
      unsigned byte = (rowbase + (unsigned)((jt * 16 + l4 * 4) * 2)) ^ swz;
      *(vh4*)((char*)attnbuf + byte) = w;
    }
  }
  __syncthreads();

  vf4 oacc[3];
#pragma unroll
  for (int nt = 0; nt < 3; ++nt) oacc[nt] = f4zero();
#pragma unroll
  for (int ks = 0; ks < 3; ++ks) {
    int arow = wave * 16 + l15;
    unsigned abyte = (unsigned)(arow * 256 + (ks * 32 + l4 * 8) * 2) ^ swzA(arow);
    vh8 pa = *(const vh8*)((const char*)attnbuf + abyte);
#pragma unroll
    for (int nt = 0; nt < 3; ++nt) {
      int n = nt * 16 + l15;
      unsigned byte = (unsigned)(n * 256 + (ks * 32 + l4 * 8) * 2) ^ swzA(n);
      vh8 vb = *(const vh8*)((const char*)vT + byte);
      oacc[nt] = __builtin_amdgcn_mfma_f32_16x16x32_f16(pa, vb, oacc[nt], 0, 0, 0);
    }
  }
#pragma unroll
  for (int nt = 0; nt < 3; ++nt) {
    int d = nt * 16 + l15;
    if (d < 40) {
#pragma unroll
      for (int r = 0; r < 4; ++r) {
        int m = wave * 16 + l4 * 4 + r;
        qt[m * 40 + d] = (_Float16)oacc[nt][r];
      }
    }
  }
  __syncthreads();

  _Float16* obase = hohm + ((size_t)(b * 8 + h) * 4096 + i0) * 40;
  {
    vh8 v = *(const vh8*)((const char*)qt + t * 16);
    *(vh8*)(obase + t * 8) = v;
  }
  if (t < 64) {
    vh8 v = *(const vh8*)((const char*)qt + (256 + t) * 16);
    *(vh8*)(obase + (256 + t) * 8) = v;
  }
}

// ---------------------------------------------------------------------------
extern "C" void kernel_launch(void* const* d_in, const int* in_sizes, int n_in,
                              void* d_out, int out_size, void* d_ws, size_t ws_size,
                              hipStream_t stream)
{
  const float* x        = (const float*)d_in[0];
  const float* embs     = (const float*)d_in[1];
  const float* cam      = (const float*)d_in[2];
  const float* progress = (const float*)d_in[3];
  const float* strength = (const float*)d_in[4];
  const float* Wq       = (const float*)d_in[5];
  const float* Wk       = (const float*)d_in[6];
  const float* Wv       = (const float*)d_in[7];
  const float* Wo       = (const float*)d_in[8];
  const float* bo       = (const float*)d_in[9];
  const float* emb1     = (const float*)d_in[10];
  const float* emb2     = (const float*)d_in[11];
  const float* Wc1      = (const float*)d_in[12];
  const float* bc1      = (const float*)d_in[13];
  const float* Wc2      = (const float*)d_in[14];
  const float* bc2      = (const float*)d_in[15];
  const int*   ctypes   = (const int*)d_in[16];

  char* w = (char*)d_ws;
  auto alloc = [&](size_t bytes) { char* p = w; w += (bytes + 255) & ~(size_t)255; return p; };
  _Float16* qhm   = (_Float16*)alloc(65536ull * 320 * 2);   // 40 MiB head-major
  _Float16* hohm  = (_Float16*)alloc(65536ull * 320 * 2);   // 40 MiB head-major
  _Float16* kvb   = (_Float16*)alloc(1232ull * 640 * 2);    // 1.5 MiB
  unsigned* vTg   = (unsigned*)alloc(128ull * 3072 * 4);    // 1.5 MiB
  _Float16* WqT   = (_Float16*)alloc(320ull * 320 * 2);
  _Float16* WkvT  = (_Float16*)alloc(640ull * 768 * 2);
  _Float16* WoT   = (_Float16*)alloc(320ull * 320 * 2);
  unsigned* lmp   = (unsigned*)alloc(65536ull * 4 * 4);     // 1 MiB
  float*    pcb   = (float*)alloc(256 * 4);
  double*   part  = (double*)alloc(4096ull * 2 * 8);        // 64 KiB
  float*    ssb   = (float*)alloc(256);
  (void)ssb;

  prep_kernel<<<696, 256, 0, stream>>>(Wq, Wk, Wv, Wo, WqT, WkvT, WoT,
                                       progress, emb1, emb2, Wc1, bc1, Wc2, bc2, pcb);
  kv_gemm_kernel<<<dim3(20, 4), 256, 0, stream>>>(embs, WkvT, kvb);
  qproj_kernel<<<640, 512, 0, stream>>>(x, WqT, kvb, ctypes, qhm, part, kvb + 320, vTg);
  lmask_kernel<<<dim3(64, 16), 256, 0, stream>>>(cam, ctypes, part, strength, lmp);
  attn_kernel<<<dim3(64, 16, 8), 256, 0, stream>>>(qhm, kvb, vTg, ctypes, pcb, lmp, hohm);
  oproj_kernel<<<512, 512, 0, stream>>>(hohm, WoT, bo, (float*)d_out);
}